// Round 11
// baseline (668.853 us; speedup 1.0000x reference)
//
#include <hip/hip_runtime.h>
#include <hip/hip_bf16.h>
#include <cstdint>
#include <cstddef>

#define NNODES 50000
#define NRELS  500
#define NEDGE  500000
#define NETOT  600000
#define MP     50048
#define RPAD   512
#define HOTN   512

typedef __attribute__((ext_vector_type(8))) short bf16x8;
typedef __attribute__((ext_vector_type(4))) float f32x4;

__device__ inline float bf2f(unsigned short s){
  union { unsigned u; float f; } v; v.u = ((unsigned)s) << 16; return v.f;
}
__device__ inline unsigned short f2bf(float f){
  __hip_bfloat16 h = __float2bfloat16(f);
  return __builtin_bit_cast(unsigned short, h);
}

// ---------------------------------------------------------------- weight conversion table
struct WEnt { int src, ld, boff, rows, K, tr, dstoff, Kp, rp; };
__device__ const WEnt g_went[18] = {
  {0,200,0,200,100,1,      0,128,256},
  {3,200,0,200,100,1,  32768,128,256},
  {1,300,  0,100,100,0,  65536,128,128},
  {1,300,100,100,100,0,  81920,128,128},
  {2,300,  0,100,100,0,  98304,128,128},
  {2,300,100,100,100,0, 114688,128,128},
  {1,300,200,100,100,0, 131072,128,128},
  {2,300,200,100,100,0, 147456,128,128},
  {4,600,  0,200,200,0, 163840,224,256},
  {4,600,200,200,200,0, 221184,224,256},
  {4,600,400,200,200,0, 278528,224,256},
  {5,600,  0,200,200,0, 335872,224,256},
  {5,600,200,200,200,0, 393216,224,256},
  {5,600,400,200,200,0, 450560,224,256},
  {6,200,0,200,200,1,   507904,224,256},
  {7,600,  0,200,200,0, 565248,224,256},
  {7,600,200,200,200,0, 622592,224,256},
  {7,600,400,200,200,0, 679936,224,256},
};
struct Ptr8 { const float* p[8]; };

// ---------------------------------------------------------------- mega setup kernel (segmented grid)
#define SB_O1 587
#define SB_O2 599
#define SB_O3 620
#define SB_O4 641
#define SB_O5 650
#define SB_O6 5342
#define SB_O7 5351
#define SB_O8 13415
#define SB_O9 25915
#define SB_TOT 26040

struct SetupArgs {
  int* iall;                               // 150001 ints (ROWOFS|CUR|MASK)
  __hip_bfloat16 *aent0, *ax1, *aent1, *arel0, *arel1;
  float* wt;
  const float *s0h, *s1h, *os0, *s1l, *os1;
  __hip_bfloat16* wa;
  Ptr8 wsrcs;
  const float *entity, *relation;
};

__global__ __launch_bounds__(256) void k_setup(SetupArgs a){
  int bid = blockIdx.x, tid = threadIdx.x;
  if (bid < SB_O1){ int i = bid*256 + tid; if (i < 150001) a.iall[i] = 0; return; }
  if (bid < SB_O2){ int i = (bid-SB_O1)*256 + tid;              // AENT0 pad rows (48x128)
    ((int*)(a.aent0 + (size_t)NNODES*128))[i] = 0; return; }
  if (bid < SB_O3){ int i = (bid-SB_O2)*256 + tid;              // AX1 pad rows (48x224)
    if (i < 5376) ((int*)(a.ax1 + (size_t)NNODES*224))[i] = 0; return; }
  if (bid < SB_O4){ int i = (bid-SB_O3)*256 + tid;              // AENT1 pad rows
    if (i < 5376) ((int*)(a.aent1 + (size_t)NNODES*224))[i] = 0; return; }
  if (bid < SB_O5){ int i = (bid-SB_O4)*256 + tid;              // AREL0/AREL1 pad rows
    if (i < 768) ((int*)(a.arel0 + (size_t)NRELS*128))[i] = 0;
    else if (i < 2112) ((int*)(a.arel1 + (size_t)NRELS*224))[i - 768] = 0;
    return; }
  if (bid < SB_O6){ int i = (bid-SB_O5)*256 + tid;              // AX1 pad cols (MP x 24)
    int r = i / 24, k = 200 + (i - r*24);
    a.ax1[(size_t)r*224 + k] = __float2bfloat16(0.f); return; }
  if (bid < SB_O7){                                             // wtab (2304)
    int i = (bid-SB_O6)*256 + tid; if (i >= 2304) return;
    float v = 0.f;
    if (i < 512){ int c = i & 127; const float* s = (i < 256) ? a.s0h : a.s1h; if (c < 100) v = s[c]; }
    else if (i < 768){ int j2 = i - 512, c = j2 & 127; const float* s = (j2 < 128) ? a.s0h : a.s1h; if (c < 100) v = s[c]; }
    else { int j2 = i - 768, t = j2 >> 9, c = j2 & 255;
           const float* s = (t==0)?a.os0:(t==1)?a.s1l:a.os1; if (c < 200) v = s[c]; }
    a.wt[i] = v; return; }
  if (bid < SB_O8){                                             // wconv (18 x 448)
    int sb = bid - SB_O7;
    WEnt e = g_went[sb / 448];
    int i = (sb - (sb/448)*448)*256 + tid;
    if (i >= e.rp*e.Kp) return;
    int r = i / e.Kp, k = i - r*e.Kp;
    float v = 0.f;
    if (r < e.rows && k < e.K)
      v = e.tr ? a.wsrcs.p[e.src][(size_t)k*e.ld + r] : a.wsrcs.p[e.src][(size_t)r*e.ld + e.boff + k];
    a.wa[e.dstoff + i] = __float2bfloat16(v); return; }
  {                                                             // l2norm -> bf16, 4 rows/block
    int wave = tid >> 6, lane = tid & 63;
    const float* src; __hip_bfloat16* dst; int row;
    if (bid < SB_O9){ row = (bid - SB_O8)*4 + wave; src = a.entity; dst = a.aent0; }
    else            { row = (bid - SB_O9)*4 + wave; src = a.relation; dst = a.arel0; }
    const float* rp = src + (size_t)row*100;
    float v0 = (lane < 100) ? rp[lane] : 0.f;
    float v1 = (lane + 64 < 100) ? rp[lane + 64] : 0.f;
    float ss = v0*v0 + v1*v1;
    #pragma unroll
    for (int o = 32; o; o >>= 1) ss += __shfl_xor(ss, o, 64);
    float sc = 1.0f / fmaxf(sqrtf(ss), 1e-12f);
    __hip_bfloat16* orow = dst + (size_t)row*128;
    orow[lane] = __float2bfloat16(v0*sc);
    orow[lane + 64] = __float2bfloat16(v1*sc);
  }
}

__global__ void k_mask_set(const int* __restrict__ batch, float* __restrict__ mask, int nb){
  int i = blockIdx.x*blockDim.x + threadIdx.x;
  if (i < nb) mask[batch[3*i+2]] = 1.0f;
}

// ---------------------------------------------------------------- edge CSR
__global__ void k_hist(const int* __restrict__ el, const int* __restrict__ nh, int* __restrict__ deg){
  int e = blockIdx.x*blockDim.x + threadIdx.x;
  if (e >= NETOT) return;
  int s = (e < NEDGE) ? el[e] : nh[4*(e-NEDGE)+3];
  atomicAdd(&deg[s], 1);
}
__global__ void k_scan1(int* __restrict__ data, int n, int* __restrict__ part){
  __shared__ int sh[256];
  int t = threadIdx.x, i = blockIdx.x*256 + t;
  int v = (i < n) ? data[i] : 0;
  sh[t] = v; __syncthreads();
  for (int o = 1; o < 256; o <<= 1){
    int x = (t >= o) ? sh[t-o] : 0;
    __syncthreads(); sh[t] += x; __syncthreads();
  }
  if (i < n) data[i] = sh[t] - v;
  if (t == 255) part[blockIdx.x] = sh[255];
}
__global__ void k_scan2(int* __restrict__ part, int nb){
  __shared__ int sh[256];
  int t = threadIdx.x;
  int v = (t < nb) ? part[t] : 0;
  sh[t] = v; __syncthreads();
  for (int o = 1; o < 256; o <<= 1){
    int x = (t >= o) ? sh[t-o] : 0;
    __syncthreads(); sh[t] += x; __syncthreads();
  }
  if (t < nb) part[t] = sh[t] - v;
}
__global__ void k_scan3(int* __restrict__ data, int n, const int* __restrict__ part){
  int i = blockIdx.x*256 + threadIdx.x;
  if (i < n) data[i] += part[blockIdx.x];
  if (i == 0) data[n] = NETOT;
}
__global__ void k_scatter(const int* __restrict__ el, const int* __restrict__ et,
                          const int* __restrict__ nh, const int* __restrict__ rowofs,
                          int* __restrict__ cur, int4* __restrict__ erec){
  int e = blockIdx.x*blockDim.x + threadIdx.x;
  if (e >= NETOT) return;
  int s, d, t0, t1;
  if (e < NEDGE){ s = el[e]; d = el[NEDGE+e]; t0 = et[e]; t1 = NRELS; }
  else { int i = e - NEDGE; s = nh[4*i+3]; d = nh[4*i+0]; t0 = nh[4*i+1]; t1 = nh[4*i+2]; }
  int p = rowofs[s] + atomicAdd(&cur[s], 1);
  erec[p] = make_int4(d, t0, t1, 0);
}

// ---------------------------------------------------------------- rel-only combine: l2norm(base + h)
template<bool FINAL>
__global__ __launch_bounds__(64) void k_combine_rel(
    const __hip_bfloat16* __restrict__ base, const __hip_bfloat16* __restrict__ h,
    float* __restrict__ outf, __hip_bfloat16* __restrict__ outb)
{
  int row = blockIdx.x, lane = threadIdx.x;
  int c = lane*4;
  float4 v = make_float4(0.f,0.f,0.f,0.f);
  if (c < 200){
    ushort4 bb = *(const ushort4*)(base + (size_t)row*224 + c);
    ushort4 hh = *(const ushort4*)(h + (size_t)row*224 + c);
    v.x = bf2f(bb.x) + bf2f(hh.x);
    v.y = bf2f(bb.y) + bf2f(hh.y);
    v.z = bf2f(bb.z) + bf2f(hh.z);
    v.w = bf2f(bb.w) + bf2f(hh.w);
  }
  float ss = v.x*v.x + v.y*v.y + v.z*v.z + v.w*v.w;
  #pragma unroll
  for (int o = 32; o; o >>= 1) ss += __shfl_xor(ss, o, 64);
  float sc = 1.0f / fmaxf(sqrtf(ss), 1e-12f);
  if constexpr (FINAL){
    if (c < 200) *(float4*)(outf + (size_t)row*200 + c) = make_float4(v.x*sc, v.y*sc, v.z*sc, v.w*sc);
  } else {
    if (c < 224){
      ushort4 w4; w4.x = f2bf(v.x*sc); w4.y = f2bf(v.y*sc); w4.z = f2bf(v.z*sc); w4.w = f2bf(v.w*sc);
      *(ushort4*)(outb + (size_t)row*224 + c) = w4;
    }
  }
}

// ---------------------------------------------------------------- fused node+rel rowdot
__global__ __launch_bounds__(256) void k_rowdot3(
    const __hip_bfloat16* __restrict__ XN, const float* __restrict__ wtN, int GN,
    float* __restrict__ n0, float* __restrict__ n1, float* __restrict__ n2, float* __restrict__ n3,
    const __hip_bfloat16* __restrict__ XR, const float* __restrict__ wtR, int GR,
    float* __restrict__ r0, float* __restrict__ r1)
{
  int wave = threadIdx.x >> 6, lane = threadIdx.x & 63;
  int b = blockIdx.x;
  if (b < 12500){
    int row = b*4 + wave;
    const __hip_bfloat16* xr = XN + (size_t)row*512 + lane*8;
    const float* wr = wtN + lane*8;
    float p = 0.f;
    #pragma unroll
    for (int k = 0; k < 2; k++){
      ushort4 x = *(const ushort4*)(xr + 4*k);
      float4 a = *(const float4*)(wr + 4*k);
      p += bf2f(x.x)*a.x + bf2f(x.y)*a.y + bf2f(x.z)*a.z + bf2f(x.w)*a.w;
    }
    for (int o = GN>>1; o; o >>= 1) p += __shfl_xor(p, o, 64);
    if ((lane & (GN-1)) == 0){
      int g = lane / GN;
      float* out = (g==0)?n0:(g==1)?n1:(g==2)?n2:n3;
      out[row] = p;
    }
  } else {
    int row = (b - 12500)*4 + wave;
    if (row >= NRELS + 1) return;
    const __hip_bfloat16* xr = XR + (size_t)row*256 + lane*4;
    ushort4 x = *(const ushort4*)xr;
    float4 a = *(const float4*)(wtR + lane*4);
    float p = bf2f(x.x)*a.x + bf2f(x.y)*a.y + bf2f(x.z)*a.z + bf2f(x.w)*a.w;
    for (int o = GR>>1; o; o >>= 1) p += __shfl_xor(p, o, 64);
    if ((lane & (GR-1)) == 0){
      int g = lane / GR;
      float* out = (g==0)?r0:r1;
      out[row] = p;
    }
  }
}

// ---------------------------------------------------------------- dual bf16 MFMA GEMM (NT)
struct GemmDesc {
  const __hip_bfloat16 *A, *B; __hip_bfloat16* C;
  int M, Nn, Kp, ldc, gx, nblk;
};
__global__ __launch_bounds__(256) void k_gemm2(GemmDesc g1, GemmDesc g2)
{
  __shared__ __hip_bfloat16 As[128*32];
  __shared__ __hip_bfloat16 Bs[64*32];
  const int tid = threadIdx.x;
  const int wave = tid >> 6, lane = tid & 63;
  const int lg = lane >> 4, li = lane & 15;
  int nwg = gridDim.x;
  int orig = blockIdx.x;
  int q = nwg >> 3, r = nwg & 7;
  int xcd = orig & 7, off = orig >> 3;
  int wg = (xcd < r ? xcd*(q+1) : r*(q+1) + (xcd - r)*q) + off;
  GemmDesc g = (wg < g1.nblk) ? g1 : g2;
  int local = (wg < g1.nblk) ? wg : wg - g1.nblk;
  const int bx = local % g.gx, by = local / g.gx;
  const int m0 = by * 128, n0 = bx * 64;
  const int Kp = g.Kp;
  const int wr = wave >> 1, wc = wave & 1;
  f32x4 acc[4][2] = {};

  const int ar0 = tid >> 2;
  const int ar1 = (tid + 256) >> 2;
  const int ap  = tid & 3;
  const char* Ab = (const char*)g.A;
  const char* Bb = (const char*)g.B;
  char* asB = (char*)As;
  char* bsB = (char*)Bs;

  for (int kk = 0; kk < Kp; kk += 32){
    {
      int p0 = ap ^ ((ar0 >> 1) & 3);
      const char* s0 = Ab + ((size_t)(m0 + ar0)*Kp + kk)*2 + p0*16;
      __builtin_amdgcn_global_load_lds((const __attribute__((address_space(1))) void*)s0,
          (__attribute__((address_space(3))) void*)(asB + wave*1024), 16, 0, 0);
      int p1 = ap ^ ((ar1 >> 1) & 3);
      const char* s1 = Ab + ((size_t)(m0 + ar1)*Kp + kk)*2 + p1*16;
      __builtin_amdgcn_global_load_lds((const __attribute__((address_space(1))) void*)s1,
          (__attribute__((address_space(3))) void*)(asB + 4096 + wave*1024), 16, 0, 0);
      int pb = ap ^ ((ar0 >> 1) & 3);
      const char* sb = Bb + ((size_t)(n0 + ar0)*Kp + kk)*2 + pb*16;
      __builtin_amdgcn_global_load_lds((const __attribute__((address_space(1))) void*)sb,
          (__attribute__((address_space(3))) void*)(bsB + wave*1024), 16, 0, 0);
    }
    __syncthreads();
    bf16x8 av[4], bv[2];
    #pragma unroll
    for (int mf = 0; mf < 4; mf++){
      int row = wr*64 + mf*16 + li;
      int p = lg ^ ((row >> 1) & 3);
      av[mf] = *(const bf16x8*)(asB + row*64 + p*16);
    }
    #pragma unroll
    for (int nf = 0; nf < 2; nf++){
      int row = wc*32 + nf*16 + li;
      int p = lg ^ ((row >> 1) & 3);
      bv[nf] = *(const bf16x8*)(bsB + row*64 + p*16);
    }
    #pragma unroll
    for (int mf = 0; mf < 4; mf++)
      #pragma unroll
      for (int nf = 0; nf < 2; nf++)
        acc[mf][nf] = __builtin_amdgcn_mfma_f32_16x16x32_bf16(av[mf], bv[nf], acc[mf][nf], 0, 0, 0);
    __syncthreads();
  }
  #pragma unroll
  for (int mf = 0; mf < 4; mf++){
    #pragma unroll
    for (int nf = 0; nf < 2; nf++){
      int gc = n0 + wc*32 + nf*16 + li;
      if (gc >= g.Nn) continue;
      int gr0 = m0 + wr*64 + mf*16 + lg*4;
      #pragma unroll
      for (int rr = 0; rr < 4; rr++){
        int gr = gr0 + rr;
        if (gr < g.M) g.C[(size_t)gr*g.ldc + gc] = __float2bfloat16(acc[mf][nf][rr]);
      }
    }
  }
}

// ---------------------------------------------------------------- aggregation (D=200), quad-edge ILP
#define EDGE_LOAD(W, D, T0, T1, OUTX, OUTY, OUTZ, OUTW)                       \
  {                                                                           \
    ushort4 xq = *(const ushort4*)(xb + (size_t)(D)*ldx);                     \
    ushort4 rq = *(const ushort4*)(rb + (size_t)(T0)*ldr);                    \
    float qx = bf2f(xq.x)+bf2f(rq.x), qy = bf2f(xq.y)+bf2f(rq.y);             \
    float qz = bf2f(xq.z)+bf2f(rq.z), qw = bf2f(xq.w)+bf2f(rq.w);             \
    if ((T1) != NRELS){                                                       \
      ushort4 rc = *(const ushort4*)(rb + (size_t)(T1)*ldr);                  \
      qx += bf2f(rc.x); qy += bf2f(rc.y); qz += bf2f(rc.z); qw += bf2f(rc.w); \
    }                                                                         \
    OUTX += (W)*qx; OUTY += (W)*qy; OUTZ += (W)*qz; OUTW += (W)*qw;           \
  }

__device__ inline void agg5_edges(int bstart, int end, int bstep,
    const int4* __restrict__ erec, float psn,
    const float* __restrict__ pd, const float* __restrict__ prs,
    const __hip_bfloat16* __restrict__ XSD, int ldx, int cxd,
    const __hip_bfloat16* __restrict__ RRb, int ldr, int crr,
    int lane, float& Sl, float4& accO)
{
  bool act = lane < 50;
  const __hip_bfloat16* xb = XSD + cxd + 4*lane;
  const __hip_bfloat16* rb = RRb + crr + 4*lane;
  float4 a0 = make_float4(0.f,0.f,0.f,0.f);
  float4 a1 = make_float4(0.f,0.f,0.f,0.f);
  float4 a2 = make_float4(0.f,0.f,0.f,0.f);
  float4 a3 = make_float4(0.f,0.f,0.f,0.f);
  for (int b = bstart; b < end; b += bstep){
    int j = b + lane;
    int4 e = make_int4(0, NRELS, NRELS, 0);
    float wv = 0.f;
    if (j < end){
      e = erec[j];
      float lg = psn + pd[e.x] + prs[e.y] + prs[e.z];
      wv = __expf(-((lg > 0.f) ? lg : 0.2f*lg));
    }
    Sl += wv;
    int m = end - b; if (m > 64) m = 64;
    int i = 0;
    for (; i + 3 < m; i += 4){
      float w0 = __shfl(wv, i),   w1 = __shfl(wv, i+1);
      float w2 = __shfl(wv, i+2), w3 = __shfl(wv, i+3);
      int d0 = __shfl(e.x, i),   u0 = __shfl(e.y, i),   v0 = __shfl(e.z, i);
      int d1 = __shfl(e.x, i+1), u1 = __shfl(e.y, i+1), v1 = __shfl(e.z, i+1);
      int d2 = __shfl(e.x, i+2), u2 = __shfl(e.y, i+2), v2 = __shfl(e.z, i+2);
      int d3 = __shfl(e.x, i+3), u3 = __shfl(e.y, i+3), v3 = __shfl(e.z, i+3);
      if (act){
        EDGE_LOAD(w0, d0, u0, v0, a0.x, a0.y, a0.z, a0.w)
        EDGE_LOAD(w1, d1, u1, v1, a1.x, a1.y, a1.z, a1.w)
        EDGE_LOAD(w2, d2, u2, v2, a2.x, a2.y, a2.z, a2.w)
        EDGE_LOAD(w3, d3, u3, v3, a3.x, a3.y, a3.z, a3.w)
      }
    }
    for (; i < m; ++i){
      float w0 = __shfl(wv, i);
      int d0 = __shfl(e.x, i), u0 = __shfl(e.y, i), v0 = __shfl(e.z, i);
      if (act){
        EDGE_LOAD(w0, d0, u0, v0, a0.x, a0.y, a0.z, a0.w)
      }
    }
  }
  accO.x += (a0.x + a1.x) + (a2.x + a3.x);
  accO.y += (a0.y + a1.y) + (a2.y + a3.y);
  accO.z += (a0.z + a1.z) + (a2.z + a3.z);
  accO.w += (a0.w + a1.w) + (a2.w + a3.w);
}

// MODE 0: bf16 out (plain). MODE 1: l2norm(base + mask*h) -> bf16 (ld224, pad cols zeroed).
// MODE 2: l2norm(base + mask*h) -> fp32 (ld200).
template<int MODE>
__device__ inline void agg5_finalize(int n, float S, float4 acc, int lane,
    const __hip_bfloat16* __restrict__ XSD, int ldx, int cxs,
    const __hip_bfloat16* __restrict__ baseb, const float* __restrict__ mask,
    __hip_bfloat16* __restrict__ outb, int ldb, int coffb, float* __restrict__ outf)
{
  float4 h = make_float4(0.f,0.f,0.f,0.f);
  if (lane < 50){
    float inv = (S > 0.f) ? 1.0f/S : 0.f;
    ushort4 xs4 = *(const ushort4*)(XSD + (size_t)n*ldx + cxs + 4*lane);
    float h0 = (S > 0.f) ? bf2f(xs4.x) + acc.x*inv : 0.f;
    float h1 = (S > 0.f) ? bf2f(xs4.y) + acc.y*inv : 0.f;
    float h2 = (S > 0.f) ? bf2f(xs4.z) + acc.z*inv : 0.f;
    float h3 = (S > 0.f) ? bf2f(xs4.w) + acc.w*inv : 0.f;
    h.x = (h0 > 0.f) ? h0 : expm1f(h0);
    h.y = (h1 > 0.f) ? h1 : expm1f(h1);
    h.z = (h2 > 0.f) ? h2 : expm1f(h2);
    h.w = (h3 > 0.f) ? h3 : expm1f(h3);
  }
  if constexpr (MODE == 0){
    if (lane < 50){
      ushort4 o; o.x = f2bf(h.x); o.y = f2bf(h.y); o.z = f2bf(h.z); o.w = f2bf(h.w);
      *(ushort4*)(outb + (size_t)n*ldb + coffb + 4*lane) = o;
    }
  } else {
    float m = mask[n];
    float4 v = make_float4(0.f,0.f,0.f,0.f);
    if (lane < 50){
      ushort4 bb = *(const ushort4*)(baseb + (size_t)n*224 + 4*lane);
      v.x = bf2f(bb.x) + m*h.x;
      v.y = bf2f(bb.y) + m*h.y;
      v.z = bf2f(bb.z) + m*h.z;
      v.w = bf2f(bb.w) + m*h.w;
    }
    float ss = v.x*v.x + v.y*v.y + v.z*v.z + v.w*v.w;
    #pragma unroll
    for (int o = 32; o; o >>= 1) ss += __shfl_xor(ss, o, 64);
    float sc = 1.0f / fmaxf(sqrtf(ss), 1e-12f);
    if constexpr (MODE == 1){
      if (lane < 56){
        ushort4 o; o.x = f2bf(v.x*sc); o.y = f2bf(v.y*sc); o.z = f2bf(v.z*sc); o.w = f2bf(v.w*sc);
        *(ushort4*)(outb + (size_t)n*224 + 4*lane) = o;   // lanes 50-55 write zeros (pad cols)
      }
    } else {
      if (lane < 50)
        *(float4*)(outf + (size_t)n*200 + 4*lane) = make_float4(v.x*sc, v.y*sc, v.z*sc, v.w*sc);
    }
  }
}

template<int MODE>
__global__ __launch_bounds__(256) void k_agg5(
    const int* __restrict__ rowofs, const int4* __restrict__ erec,
    const float* __restrict__ ps, const float* __restrict__ pd, const float* __restrict__ prs,
    const __hip_bfloat16* __restrict__ XSD,
    const __hip_bfloat16* __restrict__ RRb,
    const __hip_bfloat16* __restrict__ baseb, const float* __restrict__ mask,
    __hip_bfloat16* __restrict__ outb, int ldb, int coffb, float* __restrict__ outf)
{
  __shared__ float4 redA[256];
  __shared__ float redS[4];
  int bid = blockIdx.x;
  int wave = threadIdx.x >> 6, lane = threadIdx.x & 63;

  if (bid < HOTN){
    int n = bid;
    int beg = rowofs[n], end = rowofs[n+1];
    float psn = ps[n];
    float Sl = 0.f;
    float4 acc = make_float4(0.f,0.f,0.f,0.f);
    agg5_edges(beg + wave*64, end, 256, erec, psn, pd, prs,
               XSD, 512, 256, RRb, 256, 0, lane, Sl, acc);
    float Sw = Sl;
    #pragma unroll
    for (int o = 32; o; o >>= 1) Sw += __shfl_xor(Sw, o, 64);
    redA[threadIdx.x] = acc;
    if (lane == 0) redS[wave] = Sw;
    __syncthreads();
    if (wave == 0){
      float4 q0 = redA[lane], q1 = redA[lane+64], q2 = redA[lane+128], q3 = redA[lane+192];
      float4 at = make_float4(q0.x+q1.x+q2.x+q3.x, q0.y+q1.y+q2.y+q3.y,
                              q0.z+q1.z+q2.z+q3.z, q0.w+q1.w+q2.w+q3.w);
      float St = redS[0] + redS[1] + redS[2] + redS[3];
      agg5_finalize<MODE>(n, St, at, lane, XSD, 512, 0, baseb, mask, outb, ldb, coffb, outf);
    }
  } else {
    int n = HOTN + (bid - HOTN)*4 + wave;
    int beg = rowofs[n], end = rowofs[n+1];
    float psn = ps[n];
    float Sl = 0.f;
    float4 acc = make_float4(0.f,0.f,0.f,0.f);
    agg5_edges(beg, end, 64, erec, psn, pd, prs,
               XSD, 512, 256, RRb, 256, 0, lane, Sl, acc);
    float S = Sl;
    #pragma unroll
    for (int o = 32; o; o >>= 1) S += __shfl_xor(S, o, 64);
    agg5_finalize<MODE>(n, S, acc, lane, XSD, 512, 0, baseb, mask, outb, ldb, coffb, outf);
  }
}

// ---------------------------------------------------------------- fused layer0-heads aggregation (quad-edge)
__device__ inline void aggh_edges(int bstart, int end, int bstep,
    const int4* __restrict__ erec,
    float ps0n, const float* __restrict__ pd0, const float* __restrict__ prs0,
    float ps1n, const float* __restrict__ pd1, const float* __restrict__ prs1,
    const __hip_bfloat16* __restrict__ XSD, int ldx,
    const __hip_bfloat16* __restrict__ RRb, int ldr,
    int lane, float& Sl0, float& Sl1, float4& accO)
{
  bool act = lane < 50;
  int head = (lane >= 25) ? 1 : 0;
  int li = lane - 25*head;
  const __hip_bfloat16* xb = XSD + (head ? 384 : 128) + 4*li;
  const __hip_bfloat16* rb = RRb + (head ? 128 : 0) + 4*li;
  float4 a0 = make_float4(0.f,0.f,0.f,0.f);
  float4 a1 = make_float4(0.f,0.f,0.f,0.f);
  float4 a2 = make_float4(0.f,0.f,0.f,0.f);
  float4 a3 = make_float4(0.f,0.f,0.f,0.f);
  for (int b = bstart; b < end; b += bstep){
    int j = b + lane;
    int4 e = make_int4(0, NRELS, NRELS, 0);
    float wv0 = 0.f, wv1 = 0.f;
    if (j < end){
      e = erec[j];
      float lg0 = ps0n + pd0[e.x] + prs0[e.y] + prs0[e.z];
      float lg1 = ps1n + pd1[e.x] + prs1[e.y] + prs1[e.z];
      wv0 = __expf(-((lg0 > 0.f) ? lg0 : 0.2f*lg0));
      wv1 = __expf(-((lg1 > 0.f) ? lg1 : 0.2f*lg1));
    }
    Sl0 += wv0; Sl1 += wv1;
    int m = end - b; if (m > 64) m = 64;
    int i = 0;
    for (; i + 3 < m; i += 4){
      float wa0 = __shfl(wv0, i),   wa1 = __shfl(wv1, i);
      float wb0 = __shfl(wv0, i+1), wb1 = __shfl(wv1, i+1);
      float wc0 = __shfl(wv0, i+2), wc1 = __shfl(wv1, i+2);
      float wd0 = __shfl(wv0, i+3), wd1 = __shfl(wv1, i+3);
      int d0 = __shfl(e.x, i),   u0 = __shfl(e.y, i),   v0 = __shfl(e.z, i);
      int d1 = __shfl(e.x, i+1), u1 = __shfl(e.y, i+1), v1 = __shfl(e.z, i+1);
      int d2 = __shfl(e.x, i+2), u2 = __shfl(e.y, i+2), v2 = __shfl(e.z, i+2);
      int d3 = __shfl(e.x, i+3), u3 = __shfl(e.y, i+3), v3 = __shfl(e.z, i+3);
      if (act){
        float wA = head ? wa1 : wa0;
        float wB = head ? wb1 : wb0;
        float wC = head ? wc1 : wc0;
        float wD = head ? wd1 : wd0;
        EDGE_LOAD(wA, d0, u0, v0, a0.x, a0.y, a0.z, a0.w)
        EDGE_LOAD(wB, d1, u1, v1, a1.x, a1.y, a1.z, a1.w)
        EDGE_LOAD(wC, d2, u2, v2, a2.x, a2.y, a2.z, a2.w)
        EDGE_LOAD(wD, d3, u3, v3, a3.x, a3.y, a3.z, a3.w)
      }
    }
    for (; i < m; ++i){
      float wa0 = __shfl(wv0, i), wa1 = __shfl(wv1, i);
      int d0 = __shfl(e.x, i), u0 = __shfl(e.y, i), v0 = __shfl(e.z, i);
      if (act){
        float wA = head ? wa1 : wa0;
        EDGE_LOAD(wA, d0, u0, v0, a0.x, a0.y, a0.z, a0.w)
      }
    }
  }
  accO.x += (a0.x + a1.x) + (a2.x + a3.x);
  accO.y += (a0.y + a1.y) + (a2.y + a3.y);
  accO.z += (a0.z + a1.z) + (a2.z + a3.z);
  accO.w += (a0.w + a1.w) + (a2.w + a3.w);
}

__device__ inline void aggh_finalize(int n, float S0, float S1, float4 acc, int lane,
    const __hip_bfloat16* __restrict__ XSD,
    __hip_bfloat16* __restrict__ outb, int ldb)
{
  if (lane >= 50) return;
  int head = (lane >= 25) ? 1 : 0;
  int li = lane - 25*head;
  float S = head ? S1 : S0;
  float inv = (S > 0.f) ? 1.0f/S : 0.f;
  ushort4 xs4 = *(const ushort4*)(XSD + (size_t)n*512 + (head ? 256 : 0) + 4*li);
  float h0 = (S > 0.f) ? bf2f(xs4.x) + acc.x*inv : 0.f;
  float h1 = (S > 0.f) ? bf2f(xs4.y) + acc.y*inv : 0.f;
  float h2 = (S > 0.f) ? bf2f(xs4.z) + acc.z*inv : 0.f;
  float h3 = (S > 0.f) ? bf2f(xs4.w) + acc.w*inv : 0.f;
  h0 = (h0 > 0.f) ? h0 : expm1f(h0);
  h1 = (h1 > 0.f) ? h1 : expm1f(h1);
  h2 = (h2 > 0.f) ? h2 : expm1f(h2);
  h3 = (h3 > 0.f) ? h3 : expm1f(h3);
  ushort4 o; o.x = f2bf(h0); o.y = f2bf(h1); o.z = f2bf(h2); o.w = f2bf(h3);
  *(ushort4*)(outb + (size_t)n*ldb + 100*head + 4*li) = o;
}

__global__ __launch_bounds__(256) void k_aggh(
    const int* __restrict__ rowofs, const int4* __restrict__ erec,
    const float* __restrict__ ps0, const float* __restrict__ pd0, const float* __restrict__ prs0,
    const float* __restrict__ ps1, const float* __restrict__ pd1, const float* __restrict__ prs1,
    const __hip_bfloat16* __restrict__ XSD, const __hip_bfloat16* __restrict__ RRb,
    __hip_bfloat16* __restrict__ outb, int ldb)
{
  __shared__ float4 redA[256];
  __shared__ float redS0[4];
  __shared__ float redS1[4];
  int bid = blockIdx.x;
  int wave = threadIdx.x >> 6, lane = threadIdx.x & 63;

  if (bid < HOTN){
    int n = bid;
    int beg = rowofs[n], end = rowofs[n+1];
    float ps0n = ps0[n], ps1n = ps1[n];
    float Sl0 = 0.f, Sl1 = 0.f;
    float4 acc = make_float4(0.f,0.f,0.f,0.f);
    aggh_edges(beg + wave*64, end, 256, erec, ps0n, pd0, prs0, ps1n, pd1, prs1,
               XSD, 512, RRb, 256, lane, Sl0, Sl1, acc);
    float Sw0 = Sl0, Sw1 = Sl1;
    #pragma unroll
    for (int o = 32; o; o >>= 1){ Sw0 += __shfl_xor(Sw0, o, 64); Sw1 += __shfl_xor(Sw1, o, 64); }
    redA[threadIdx.x] = acc;
    if (lane == 0){ redS0[wave] = Sw0; redS1[wave] = Sw1; }
    __syncthreads();
    if (wave == 0){
      float4 q0 = redA[lane], q1 = redA[lane+64], q2 = redA[lane+128], q3 = redA[lane+192];
      float4 at = make_float4(q0.x+q1.x+q2.x+q3.x, q0.y+q1.y+q2.y+q3.y,
                              q0.z+q1.z+q2.z+q3.z, q0.w+q1.w+q2.w+q3.w);
      float St0 = redS0[0] + redS0[1] + redS0[2] + redS0[3];
      float St1 = redS1[0] + redS1[1] + redS1[2] + redS1[3];
      aggh_finalize(n, St0, St1, at, lane, XSD, outb, ldb);
    }
  } else {
    int n = HOTN + (bid - HOTN)*4 + wave;
    int beg = rowofs[n], end = rowofs[n+1];
    float ps0n = ps0[n], ps1n = ps1[n];
    float Sl0 = 0.f, Sl1 = 0.f;
    float4 acc = make_float4(0.f,0.f,0.f,0.f);
    aggh_edges(beg, end, 64, erec, ps0n, pd0, prs0, ps1n, pd1, prs1,
               XSD, 512, RRb, 256, lane, Sl0, Sl1, acc);
    float S0 = Sl0, S1 = Sl1;
    #pragma unroll
    for (int o = 32; o; o >>= 1){ S0 += __shfl_xor(S0, o, 64); S1 += __shfl_xor(S1, o, 64); }
    aggh_finalize(n, S0, S1, acc, lane, XSD, outb, ldb);
  }
}

// ---------------------------------------------------------------- driver
extern "C" void kernel_launch(void* const* d_in, const int* in_sizes, int n_in,
                              void* d_out, int out_size, void* d_ws, size_t ws_size,
                              hipStream_t stream) {
  const float* entity   = (const float*)d_in[0];
  const float* relation = (const float*)d_in[1];
  const float* W_ent    = (const float*)d_in[2];
  const float* g0_a0    = (const float*)d_in[3];
  const float* g0_s0    = (const float*)d_in[4];
  const float* g0_a1    = (const float*)d_in[5];
  const float* g0_s1    = (const float*)d_in[6];
  const float* g0_W     = (const float*)d_in[7];
  const float* g0_oa    = (const float*)d_in[8];
  const float* g0_os    = (const float*)d_in[9];
  const float* g1_a0    = (const float*)d_in[10];
  const float* g1_s0    = (const float*)d_in[11];
  const float* g1_W     = (const float*)d_in[12];
  const float* g1_oa    = (const float*)d_in[13];
  const float* g1_os    = (const float*)d_in[14];
  const int*   el       = (const int*)d_in[15];
  const int*   et       = (const int*)d_in[16];
  const int*   nh       = (const int*)d_in[17];
  const int*   batch    = (const int*)d_in[18];
  (void)in_sizes; (void)n_in; (void)out_size; (void)ws_size;

  char* w = (char*)d_ws;
  auto alloc = [&](size_t bytes)->char*{ char* p = w; w += (bytes + 255) & ~(size_t)255; return p; };
  float* PS0   = (float*)alloc((size_t)NNODES*4);
  float* PD0   = (float*)alloc((size_t)NNODES*4);
  float* PS1   = (float*)alloc((size_t)NNODES*4);
  float* PD1   = (float*)alloc((size_t)NNODES*4);
  float* PRS0  = (float*)alloc((size_t)(NRELS+4)*4);
  float* PRS1  = (float*)alloc((size_t)(NRELS+4)*4);
  float* WT    = (float*)alloc((size_t)2304*4);
  __hip_bfloat16* AENT0  = (__hip_bfloat16*)alloc((size_t)MP*128*2);
  __hip_bfloat16* AX1    = (__hip_bfloat16*)alloc((size_t)MP*224*2);
  __hip_bfloat16* AENT1  = (__hip_bfloat16*)alloc((size_t)MP*224*2);
  __hip_bfloat16* ENTUPb = (__hip_bfloat16*)alloc((size_t)MP*224*2);
  __hip_bfloat16* AREL0  = (__hip_bfloat16*)alloc((size_t)RPAD*128*2);
  __hip_bfloat16* AREL1  = (__hip_bfloat16*)alloc((size_t)RPAD*224*2);
  __hip_bfloat16* RELUPb = (__hip_bfloat16*)alloc((size_t)RPAD*224*2);
  __hip_bfloat16* ORb0   = (__hip_bfloat16*)alloc((size_t)RPAD*224*2);
  __hip_bfloat16* ORb1   = (__hip_bfloat16*)alloc((size_t)RPAD*224*2);
  __hip_bfloat16* XSD    = (__hip_bfloat16*)alloc((size_t)MP*512*2);
  __hip_bfloat16* RRb    = (__hip_bfloat16*)alloc((size_t)RPAD*256*2);
  __hip_bfloat16* WA     = (__hip_bfloat16*)alloc((size_t)737280*2);
  int* IALL = (int*)alloc((size_t)150001*4);
  int* ROWOFS = IALL;
  int* CUR    = IALL + 50001;
  float* MASK = (float*)(IALL + 100001);
  int4* EREC  = (int4*)alloc((size_t)NETOT*16);
  int* PART   = (int*)alloc((size_t)256*4);

  const __hip_bfloat16* WET   = WA;
  const __hip_bfloat16* G0WT  = WA + 32768;
  const __hip_bfloat16* BH0   = WA + 65536;
  const __hip_bfloat16* BR0   = WA + 131072;
  const __hip_bfloat16* BO0   = WA + 163840;
  const __hip_bfloat16* BO0r  = WA + 278528;
  const __hip_bfloat16* BA1   = WA + 335872;
  const __hip_bfloat16* BA1r  = WA + 450560;
  const __hip_bfloat16* G1WT  = WA + 507904;
  const __hip_bfloat16* BO1   = WA + 565248;
  const __hip_bfloat16* BO1r  = WA + 679936;

  float* outEnt = (float*)d_out;
  float* outRel = outEnt + (size_t)NNODES*200;

  const int TB = 256;
  auto gb = [&](long long n){ return (int)((n + TB - 1)/TB); };
  const int AGG_GRID = HOTN + (NNODES - HOTN)/4;
  const int RD_GRID = 12500 + 126;

  // ---- setup ----
  {
    SetupArgs a;
    a.iall = IALL; a.aent0 = AENT0; a.ax1 = AX1; a.aent1 = AENT1; a.arel0 = AREL0; a.arel1 = AREL1;
    a.wt = WT; a.s0h = g0_s0; a.s1h = g0_s1; a.os0 = g0_os; a.s1l = g1_s0; a.os1 = g1_os;
    a.wa = WA;
    a.wsrcs.p[0] = W_ent; a.wsrcs.p[1] = g0_a0; a.wsrcs.p[2] = g0_a1; a.wsrcs.p[3] = g0_W;
    a.wsrcs.p[4] = g0_oa; a.wsrcs.p[5] = g1_a0; a.wsrcs.p[6] = g1_W;  a.wsrcs.p[7] = g1_oa;
    a.entity = entity; a.relation = relation;
    k_setup<<<SB_TOT, 256, 0, stream>>>(a);
  }
  k_mask_set<<<gb(10000), TB, 0, stream>>>(batch, MASK, 10000);
  k_hist<<<gb(NETOT), TB, 0, stream>>>(el, nh, ROWOFS);
  int nsb = (NNODES + 255)/256;
  k_scan1<<<nsb, 256, 0, stream>>>(ROWOFS, NNODES, PART);
  k_scan2<<<1, 256, 0, stream>>>(PART, nsb);
  k_scan3<<<nsb, 256, 0, stream>>>(ROWOFS, NNODES, PART);
  k_scatter<<<gb(NETOT), TB, 0, stream>>>(el, et, nh, ROWOFS, CUR, EREC);

  auto mkdesc = [](const __hip_bfloat16* A, const __hip_bfloat16* B, __hip_bfloat16* C,
                   int M, int Nn, int Kp, int ldc){
    GemmDesc d; d.A = A; d.B = B; d.C = C; d.M = M; d.Nn = Nn; d.Kp = Kp; d.ldc = ldc;
    d.gx = (Nn + 63)/64; d.nblk = d.gx * ((M + 127)/128); return d;
  };
  GemmDesc dnull = {}; dnull.nblk = 0;
  auto gemm2 = [&](GemmDesc d1, GemmDesc d2){
    k_gemm2<<<d1.nblk + d2.nblk, 256, 0, stream>>>(d1, d2);
  };

  // ---- ent_up / rel_up ----
  gemm2(mkdesc(AENT0, WET, ENTUPb, MP, 200, 128, 224),
        mkdesc(AREL0, WET, RELUPb, RPAD, 200, 128, 224));

  // ---- layer0 heads ----
  gemm2(mkdesc(AENT0, BH0, XSD, MP, 512, 128, 512),
        mkdesc(AREL0, BR0, RRb, RPAD, 256, 128, 256));
  k_rowdot3<<<RD_GRID, 256, 0, stream>>>(XSD, WT + 0, 16, PS0, PD0, PS1, PD1,
                                         RRb, WT + 512, 32, PRS0, PRS1);
  k_aggh<<<AGG_GRID, 256, 0, stream>>>(ROWOFS, EREC, PS0, PD0, PRS0, PS1, PD1, PRS1,
                                       XSD, RRb, AX1, 224);

  // ---- layer0 out-attention (agg fused with combine -> AENT1) ----
  gemm2(mkdesc(AX1, BO0, XSD, MP, 512, 224, 512),
        mkdesc(AREL0, G0WT, ORb0, RPAD, 224, 128, 224));
  gemm2(mkdesc(ORb0, BO0r, RRb, RPAD, 256, 224, 256), dnull);
  k_rowdot3<<<RD_GRID, 256, 0, stream>>>(XSD, WT + 768, 32, PS0, PD0, nullptr, nullptr,
                                         RRb, WT + 768, 64, PRS0, nullptr);
  k_agg5<1><<<AGG_GRID, 256, 0, stream>>>(ROWOFS, EREC, PS0, PD0, PRS0, XSD, RRb,
                                          ENTUPb, MASK, AENT1, 224, 0, nullptr);
  k_combine_rel<false><<<NRELS, 64, 0, stream>>>(RELUPb, ORb0, nullptr, AREL1);

  // ---- layer1 head ----
  gemm2(mkdesc(AENT1, BA1, XSD, MP, 512, 224, 512),
        mkdesc(AREL1, BA1r, RRb, RPAD, 256, 224, 256));
  k_rowdot3<<<RD_GRID, 256, 0, stream>>>(XSD, WT + 1280, 32, PS0, PD0, nullptr, nullptr,
                                         RRb, WT + 1280, 64, PRS0, nullptr);
  k_agg5<0><<<AGG_GRID, 256, 0, stream>>>(ROWOFS, EREC, PS0, PD0, PRS0, XSD, RRb,
                                          nullptr, nullptr, AX1, 224, 0, nullptr);

  // ---- layer1 out-attention (agg fused with final combine -> d_out) ----
  gemm2(mkdesc(AX1, BO1, XSD, MP, 512, 224, 512),
        mkdesc(AREL1, G1WT, ORb1, RPAD, 224, 224, 224));
  gemm2(mkdesc(ORb1, BO1r, RRb, RPAD, 256, 224, 256), dnull);
  k_rowdot3<<<RD_GRID, 256, 0, stream>>>(XSD, WT + 1792, 32, PS0, PD0, nullptr, nullptr,
                                         RRb, WT + 1792, 64, PRS0, nullptr);
  k_agg5<2><<<AGG_GRID, 256, 0, stream>>>(ROWOFS, EREC, PS0, PD0, PRS0, XSD, RRb,
                                          AENT1, MASK, nullptr, 0, 0, outEnt);
  k_combine_rel<true><<<NRELS, 64, 0, stream>>>(AREL1, ORb1, outRel, nullptr);
}

// Round 12
// 563.002 us; speedup vs baseline: 1.1880x; 1.1880x over previous
//
#include <hip/hip_runtime.h>
#include <hip/hip_bf16.h>
#include <cstdint>
#include <cstddef>

#define NNODES 50000
#define NRELS  500
#define NEDGE  500000
#define NETOT  600000
#define MP     50048
#define RPAD   512
#define HOTN   512

typedef __attribute__((ext_vector_type(8))) short bf16x8;
typedef __attribute__((ext_vector_type(4))) float f32x4;

__device__ inline float bf2f(unsigned short s){
  union { unsigned u; float f; } v; v.u = ((unsigned)s) << 16; return v.f;
}
__device__ inline unsigned short f2bf(float f){
  __hip_bfloat16 h = __float2bfloat16(f);
  return __builtin_bit_cast(unsigned short, h);
}

// ---------------------------------------------------------------- weight conversion table
struct WEnt { int src, ld, boff, rows, K, tr, dstoff, Kp, rp; };
__device__ const WEnt g_went[18] = {
  {0,200,0,200,100,1,      0,128,256},
  {3,200,0,200,100,1,  32768,128,256},
  {1,300,  0,100,100,0,  65536,128,128},
  {1,300,100,100,100,0,  81920,128,128},
  {2,300,  0,100,100,0,  98304,128,128},
  {2,300,100,100,100,0, 114688,128,128},
  {1,300,200,100,100,0, 131072,128,128},
  {2,300,200,100,100,0, 147456,128,128},
  {4,600,  0,200,200,0, 163840,224,256},
  {4,600,200,200,200,0, 221184,224,256},
  {4,600,400,200,200,0, 278528,224,256},
  {5,600,  0,200,200,0, 335872,224,256},
  {5,600,200,200,200,0, 393216,224,256},
  {5,600,400,200,200,0, 450560,224,256},
  {6,200,0,200,200,1,   507904,224,256},
  {7,600,  0,200,200,0, 565248,224,256},
  {7,600,200,200,200,0, 622592,224,256},
  {7,600,400,200,200,0, 679936,224,256},
};
struct Ptr8 { const float* p[8]; };

// ---------------------------------------------------------------- mega setup kernel (segmented grid)
#define SB_O1 587
#define SB_O2 599
#define SB_O3 620
#define SB_O4 641
#define SB_O5 650
#define SB_O6 5342
#define SB_O7 5351
#define SB_O8 13415
#define SB_O9 25915
#define SB_TOT 26040

struct SetupArgs {
  int* iall;                               // 150001 ints (ROWOFS|CUR|MASK)
  __hip_bfloat16 *aent0, *ax1, *aent1, *arel0, *arel1;
  float* wt;
  const float *s0h, *s1h, *os0, *s1l, *os1;
  __hip_bfloat16* wa;
  Ptr8 wsrcs;
  const float *entity, *relation;
};

__global__ __launch_bounds__(256) void k_setup(SetupArgs a){
  int bid = blockIdx.x, tid = threadIdx.x;
  if (bid < SB_O1){ int i = bid*256 + tid; if (i < 150001) a.iall[i] = 0; return; }
  if (bid < SB_O2){ int i = (bid-SB_O1)*256 + tid;
    ((int*)(a.aent0 + (size_t)NNODES*128))[i] = 0; return; }
  if (bid < SB_O3){ int i = (bid-SB_O2)*256 + tid;
    if (i < 5376) ((int*)(a.ax1 + (size_t)NNODES*224))[i] = 0; return; }
  if (bid < SB_O4){ int i = (bid-SB_O3)*256 + tid;
    if (i < 5376) ((int*)(a.aent1 + (size_t)NNODES*224))[i] = 0; return; }
  if (bid < SB_O5){ int i = (bid-SB_O4)*256 + tid;
    if (i < 768) ((int*)(a.arel0 + (size_t)NRELS*128))[i] = 0;
    else if (i < 2112) ((int*)(a.arel1 + (size_t)NRELS*224))[i - 768] = 0;
    return; }
  if (bid < SB_O6){ int i = (bid-SB_O5)*256 + tid;
    int r = i / 24, k = 200 + (i - r*24);
    a.ax1[(size_t)r*224 + k] = __float2bfloat16(0.f); return; }
  if (bid < SB_O7){
    int i = (bid-SB_O6)*256 + tid; if (i >= 2304) return;
    float v = 0.f;
    if (i < 512){ int c = i & 127; const float* s = (i < 256) ? a.s0h : a.s1h; if (c < 100) v = s[c]; }
    else if (i < 768){ int j2 = i - 512, c = j2 & 127; const float* s = (j2 < 128) ? a.s0h : a.s1h; if (c < 100) v = s[c]; }
    else { int j2 = i - 768, t = j2 >> 9, c = j2 & 255;
           const float* s = (t==0)?a.os0:(t==1)?a.s1l:a.os1; if (c < 200) v = s[c]; }
    a.wt[i] = v; return; }
  if (bid < SB_O8){
    int sb = bid - SB_O7;
    WEnt e = g_went[sb / 448];
    int i = (sb - (sb/448)*448)*256 + tid;
    if (i >= e.rp*e.Kp) return;
    int r = i / e.Kp, k = i - r*e.Kp;
    float v = 0.f;
    if (r < e.rows && k < e.K)
      v = e.tr ? a.wsrcs.p[e.src][(size_t)k*e.ld + r] : a.wsrcs.p[e.src][(size_t)r*e.ld + e.boff + k];
    a.wa[e.dstoff + i] = __float2bfloat16(v); return; }
  {
    int wave = tid >> 6, lane = tid & 63;
    const float* src; __hip_bfloat16* dst; int row;
    if (bid < SB_O9){ row = (bid - SB_O8)*4 + wave; src = a.entity; dst = a.aent0; }
    else            { row = (bid - SB_O9)*4 + wave; src = a.relation; dst = a.arel0; }
    const float* rp = src + (size_t)row*100;
    float v0 = (lane < 100) ? rp[lane] : 0.f;
    float v1 = (lane + 64 < 100) ? rp[lane + 64] : 0.f;
    float ss = v0*v0 + v1*v1;
    #pragma unroll
    for (int o = 32; o; o >>= 1) ss += __shfl_xor(ss, o, 64);
    float sc = 1.0f / fmaxf(sqrtf(ss), 1e-12f);
    __hip_bfloat16* orow = dst + (size_t)row*128;
    orow[lane] = __float2bfloat16(v0*sc);
    orow[lane + 64] = __float2bfloat16(v1*sc);
  }
}

__global__ void k_mask_set(const int* __restrict__ batch, float* __restrict__ mask, int nb){
  int i = blockIdx.x*blockDim.x + threadIdx.x;
  if (i < nb) mask[batch[3*i+2]] = 1.0f;
}

// ---------------------------------------------------------------- edge CSR
__global__ void k_hist(const int* __restrict__ el, const int* __restrict__ nh, int* __restrict__ deg){
  int e = blockIdx.x*blockDim.x + threadIdx.x;
  if (e >= NETOT) return;
  int s = (e < NEDGE) ? el[e] : nh[4*(e-NEDGE)+3];
  atomicAdd(&deg[s], 1);
}
__global__ void k_scan1(int* __restrict__ data, int n, int* __restrict__ part){
  __shared__ int sh[256];
  int t = threadIdx.x, i = blockIdx.x*256 + t;
  int v = (i < n) ? data[i] : 0;
  sh[t] = v; __syncthreads();
  for (int o = 1; o < 256; o <<= 1){
    int x = (t >= o) ? sh[t-o] : 0;
    __syncthreads(); sh[t] += x; __syncthreads();
  }
  if (i < n) data[i] = sh[t] - v;
  if (t == 255) part[blockIdx.x] = sh[255];
}
__global__ void k_scan2(int* __restrict__ part, int nb){
  __shared__ int sh[256];
  int t = threadIdx.x;
  int v = (t < nb) ? part[t] : 0;
  sh[t] = v; __syncthreads();
  for (int o = 1; o < 256; o <<= 1){
    int x = (t >= o) ? sh[t-o] : 0;
    __syncthreads(); sh[t] += x; __syncthreads();
  }
  if (t < nb) part[t] = sh[t] - v;
}
__global__ void k_scan3(int* __restrict__ data, int n, const int* __restrict__ part){
  int i = blockIdx.x*256 + threadIdx.x;
  if (i < n) data[i] += part[blockIdx.x];
  if (i == 0) data[n] = NETOT;
}
__global__ void k_scatter(const int* __restrict__ el, const int* __restrict__ et,
                          const int* __restrict__ nh, const int* __restrict__ rowofs,
                          int* __restrict__ cur, int4* __restrict__ erec){
  int e = blockIdx.x*blockDim.x + threadIdx.x;
  if (e >= NETOT) return;
  int s, d, t0, t1;
  if (e < NEDGE){ s = el[e]; d = el[NEDGE+e]; t0 = et[e]; t1 = NRELS; }
  else { int i = e - NEDGE; s = nh[4*i+3]; d = nh[4*i+0]; t0 = nh[4*i+1]; t1 = nh[4*i+2]; }
  int p = rowofs[s] + atomicAdd(&cur[s], 1);
  erec[p] = make_int4(d, t0, t1, 0);
}

// ---------------------------------------------------------------- rel-only combine: l2norm(base + h)
template<bool FINAL>
__global__ __launch_bounds__(64) void k_combine_rel(
    const __hip_bfloat16* __restrict__ base, const __hip_bfloat16* __restrict__ h,
    float* __restrict__ outf, __hip_bfloat16* __restrict__ outb)
{
  int row = blockIdx.x, lane = threadIdx.x;
  int c = lane*4;
  float4 v = make_float4(0.f,0.f,0.f,0.f);
  if (c < 200){
    ushort4 bb = *(const ushort4*)(base + (size_t)row*224 + c);
    ushort4 hh = *(const ushort4*)(h + (size_t)row*224 + c);
    v.x = bf2f(bb.x) + bf2f(hh.x);
    v.y = bf2f(bb.y) + bf2f(hh.y);
    v.z = bf2f(bb.z) + bf2f(hh.z);
    v.w = bf2f(bb.w) + bf2f(hh.w);
  }
  float ss = v.x*v.x + v.y*v.y + v.z*v.z + v.w*v.w;
  #pragma unroll
  for (int o = 32; o; o >>= 1) ss += __shfl_xor(ss, o, 64);
  float sc = 1.0f / fmaxf(sqrtf(ss), 1e-12f);
  if constexpr (FINAL){
    if (c < 200) *(float4*)(outf + (size_t)row*200 + c) = make_float4(v.x*sc, v.y*sc, v.z*sc, v.w*sc);
  } else {
    if (c < 224){
      ushort4 w4; w4.x = f2bf(v.x*sc); w4.y = f2bf(v.y*sc); w4.z = f2bf(v.z*sc); w4.w = f2bf(v.w*sc);
      *(ushort4*)(outb + (size_t)row*224 + c) = w4;
    }
  }
}

// ---------------------------------------------------------------- fused node+rel rowdot
__global__ __launch_bounds__(256) void k_rowdot3(
    const __hip_bfloat16* __restrict__ XN, const float* __restrict__ wtN, int GN,
    float* __restrict__ n0, float* __restrict__ n1, float* __restrict__ n2, float* __restrict__ n3,
    const __hip_bfloat16* __restrict__ XR, const float* __restrict__ wtR, int GR,
    float* __restrict__ r0, float* __restrict__ r1)
{
  int wave = threadIdx.x >> 6, lane = threadIdx.x & 63;
  int b = blockIdx.x;
  if (b < 12500){
    int row = b*4 + wave;
    const __hip_bfloat16* xr = XN + (size_t)row*512 + lane*8;
    const float* wr = wtN + lane*8;
    float p = 0.f;
    #pragma unroll
    for (int k = 0; k < 2; k++){
      ushort4 x = *(const ushort4*)(xr + 4*k);
      float4 a = *(const float4*)(wr + 4*k);
      p += bf2f(x.x)*a.x + bf2f(x.y)*a.y + bf2f(x.z)*a.z + bf2f(x.w)*a.w;
    }
    for (int o = GN>>1; o; o >>= 1) p += __shfl_xor(p, o, 64);
    if ((lane & (GN-1)) == 0){
      int g = lane / GN;
      float* out = (g==0)?n0:(g==1)?n1:(g==2)?n2:n3;
      out[row] = p;
    }
  } else {
    int row = (b - 12500)*4 + wave;
    if (row >= NRELS + 1) return;
    const __hip_bfloat16* xr = XR + (size_t)row*256 + lane*4;
    ushort4 x = *(const ushort4*)xr;
    float4 a = *(const float4*)(wtR + lane*4);
    float p = bf2f(x.x)*a.x + bf2f(x.y)*a.y + bf2f(x.z)*a.z + bf2f(x.w)*a.w;
    for (int o = GR>>1; o; o >>= 1) p += __shfl_xor(p, o, 64);
    if ((lane & (GR-1)) == 0){
      int g = lane / GR;
      float* out = (g==0)?r0:r1;
      out[row] = p;
    }
  }
}

// ---------------------------------------------------------------- dual bf16 MFMA GEMM (NT)
struct GemmDesc {
  const __hip_bfloat16 *A, *B; __hip_bfloat16* C;
  int M, Nn, Kp, ldc, gx, nblk;
};
__global__ __launch_bounds__(256) void k_gemm2(GemmDesc g1, GemmDesc g2)
{
  __shared__ __hip_bfloat16 As[128*32];
  __shared__ __hip_bfloat16 Bs[64*32];
  const int tid = threadIdx.x;
  const int wave = tid >> 6, lane = tid & 63;
  const int lg = lane >> 4, li = lane & 15;
  int nwg = gridDim.x;
  int orig = blockIdx.x;
  int q = nwg >> 3, r = nwg & 7;
  int xcd = orig & 7, off = orig >> 3;
  int wg = (xcd < r ? xcd*(q+1) : r*(q+1) + (xcd - r)*q) + off;
  GemmDesc g = (wg < g1.nblk) ? g1 : g2;
  int local = (wg < g1.nblk) ? wg : wg - g1.nblk;
  const int bx = local % g.gx, by = local / g.gx;
  const int m0 = by * 128, n0 = bx * 64;
  const int Kp = g.Kp;
  const int wr = wave >> 1, wc = wave & 1;
  f32x4 acc[4][2] = {};

  const int ar0 = tid >> 2;
  const int ar1 = (tid + 256) >> 2;
  const int ap  = tid & 3;
  const char* Ab = (const char*)g.A;
  const char* Bb = (const char*)g.B;
  char* asB = (char*)As;
  char* bsB = (char*)Bs;

  for (int kk = 0; kk < Kp; kk += 32){
    {
      int p0 = ap ^ ((ar0 >> 1) & 3);
      const char* s0 = Ab + ((size_t)(m0 + ar0)*Kp + kk)*2 + p0*16;
      __builtin_amdgcn_global_load_lds((const __attribute__((address_space(1))) void*)s0,
          (__attribute__((address_space(3))) void*)(asB + wave*1024), 16, 0, 0);
      int p1 = ap ^ ((ar1 >> 1) & 3);
      const char* s1 = Ab + ((size_t)(m0 + ar1)*Kp + kk)*2 + p1*16;
      __builtin_amdgcn_global_load_lds((const __attribute__((address_space(1))) void*)s1,
          (__attribute__((address_space(3))) void*)(asB + 4096 + wave*1024), 16, 0, 0);
      int pb = ap ^ ((ar0 >> 1) & 3);
      const char* sb = Bb + ((size_t)(n0 + ar0)*Kp + kk)*2 + pb*16;
      __builtin_amdgcn_global_load_lds((const __attribute__((address_space(1))) void*)sb,
          (__attribute__((address_space(3))) void*)(bsB + wave*1024), 16, 0, 0);
    }
    __syncthreads();
    bf16x8 av[4], bv[2];
    #pragma unroll
    for (int mf = 0; mf < 4; mf++){
      int row = wr*64 + mf*16 + li;
      int p = lg ^ ((row >> 1) & 3);
      av[mf] = *(const bf16x8*)(asB + row*64 + p*16);
    }
    #pragma unroll
    for (int nf = 0; nf < 2; nf++){
      int row = wc*32 + nf*16 + li;
      int p = lg ^ ((row >> 1) & 3);
      bv[nf] = *(const bf16x8*)(bsB + row*64 + p*16);
    }
    #pragma unroll
    for (int mf = 0; mf < 4; mf++)
      #pragma unroll
      for (int nf = 0; nf < 2; nf++)
        acc[mf][nf] = __builtin_amdgcn_mfma_f32_16x16x32_bf16(av[mf], bv[nf], acc[mf][nf], 0, 0, 0);
    __syncthreads();
  }
  #pragma unroll
  for (int mf = 0; mf < 4; mf++){
    #pragma unroll
    for (int nf = 0; nf < 2; nf++){
      int gc = n0 + wc*32 + nf*16 + li;
      if (gc >= g.Nn) continue;
      int gr0 = m0 + wr*64 + mf*16 + lg*4;
      #pragma unroll
      for (int rr = 0; rr < 4; rr++){
        int gr = gr0 + rr;
        if (gr < g.M) g.C[(size_t)gr*g.ldc + gc] = __float2bfloat16(acc[mf][nf][rr]);
      }
    }
  }
}

// ---------------------------------------------------------------- aggregation (D=200), shfl dual-edge ILP
__device__ inline void agg5_edges(int bstart, int end, int bstep,
    const int4* __restrict__ erec, float psn,
    const float* __restrict__ pd, const float* __restrict__ prs,
    const __hip_bfloat16* __restrict__ XSD, int ldx, int cxd,
    const __hip_bfloat16* __restrict__ RRb, int ldr, int crr,
    int lane, float& Sl, float4& accO)
{
  bool act = lane < 50;
  const __hip_bfloat16* xb = XSD + cxd + 4*lane;
  const __hip_bfloat16* rb = RRb + crr + 4*lane;
  float4 accA = make_float4(0.f,0.f,0.f,0.f);
  float4 accB = make_float4(0.f,0.f,0.f,0.f);
  for (int b = bstart; b < end; b += bstep){
    int j = b + lane;
    int4 e = make_int4(0, NRELS, NRELS, 0);
    float wv = 0.f;
    if (j < end){
      e = erec[j];
      float lg = psn + pd[e.x] + prs[e.y] + prs[e.z];
      wv = __expf(-((lg > 0.f) ? lg : 0.2f*lg));
    }
    Sl += wv;
    int m = end - b; if (m > 64) m = 64;
    int i = 0;
    for (; i + 1 < m; i += 2){
      float wA = __shfl(wv, i),   wB = __shfl(wv, i+1);
      int dA = __shfl(e.x, i),   tA0 = __shfl(e.y, i),   tA1 = __shfl(e.z, i);
      int dB = __shfl(e.x, i+1), tB0 = __shfl(e.y, i+1), tB1 = __shfl(e.z, i+1);
      if (act){
        ushort4 xA = *(const ushort4*)(xb + (size_t)dA*ldx);
        ushort4 rA = *(const ushort4*)(rb + (size_t)tA0*ldr);
        ushort4 xB = *(const ushort4*)(xb + (size_t)dB*ldx);
        ushort4 rB = *(const ushort4*)(rb + (size_t)tB0*ldr);
        float ax = bf2f(xA.x)+bf2f(rA.x), ay = bf2f(xA.y)+bf2f(rA.y);
        float az = bf2f(xA.z)+bf2f(rA.z), aw = bf2f(xA.w)+bf2f(rA.w);
        if (tA1 != NRELS){
          ushort4 rc = *(const ushort4*)(rb + (size_t)tA1*ldr);
          ax += bf2f(rc.x); ay += bf2f(rc.y); az += bf2f(rc.z); aw += bf2f(rc.w);
        }
        float bx = bf2f(xB.x)+bf2f(rB.x), by = bf2f(xB.y)+bf2f(rB.y);
        float bz = bf2f(xB.z)+bf2f(rB.z), bw = bf2f(xB.w)+bf2f(rB.w);
        if (tB1 != NRELS){
          ushort4 rc = *(const ushort4*)(rb + (size_t)tB1*ldr);
          bx += bf2f(rc.x); by += bf2f(rc.y); bz += bf2f(rc.z); bw += bf2f(rc.w);
        }
        accA.x += wA*ax; accA.y += wA*ay; accA.z += wA*az; accA.w += wA*aw;
        accB.x += wB*bx; accB.y += wB*by; accB.z += wB*bz; accB.w += wB*bw;
      }
    }
    if (i < m){
      float wA = __shfl(wv, i);
      int dA = __shfl(e.x, i), tA0 = __shfl(e.y, i), tA1 = __shfl(e.z, i);
      if (act){
        ushort4 xA = *(const ushort4*)(xb + (size_t)dA*ldx);
        ushort4 rA = *(const ushort4*)(rb + (size_t)tA0*ldr);
        float ax = bf2f(xA.x)+bf2f(rA.x), ay = bf2f(xA.y)+bf2f(rA.y);
        float az = bf2f(xA.z)+bf2f(rA.z), aw = bf2f(xA.w)+bf2f(rA.w);
        if (tA1 != NRELS){
          ushort4 rc = *(const ushort4*)(rb + (size_t)tA1*ldr);
          ax += bf2f(rc.x); ay += bf2f(rc.y); az += bf2f(rc.z); aw += bf2f(rc.w);
        }
        accA.x += wA*ax; accA.y += wA*ay; accA.z += wA*az; accA.w += wA*aw;
      }
    }
  }
  accO.x += accA.x + accB.x; accO.y += accA.y + accB.y;
  accO.z += accA.z + accB.z; accO.w += accA.w + accB.w;
}

// MODE 0: bf16 out (plain). MODE 1: l2norm(base + mask*h) -> bf16 (ld224, pad cols zeroed).
// MODE 2: l2norm(base + mask*h) -> fp32 (ld200).
template<int MODE>
__device__ inline void agg5_finalize(int n, float S, float4 acc, int lane,
    const __hip_bfloat16* __restrict__ XSD, int ldx, int cxs,
    const __hip_bfloat16* __restrict__ baseb, const float* __restrict__ mask,
    __hip_bfloat16* __restrict__ outb, int ldb, int coffb, float* __restrict__ outf)
{
  float4 h = make_float4(0.f,0.f,0.f,0.f);
  if (lane < 50){
    float inv = (S > 0.f) ? 1.0f/S : 0.f;
    ushort4 xs4 = *(const ushort4*)(XSD + (size_t)n*ldx + cxs + 4*lane);
    float h0 = (S > 0.f) ? bf2f(xs4.x) + acc.x*inv : 0.f;
    float h1 = (S > 0.f) ? bf2f(xs4.y) + acc.y*inv : 0.f;
    float h2 = (S > 0.f) ? bf2f(xs4.z) + acc.z*inv : 0.f;
    float h3 = (S > 0.f) ? bf2f(xs4.w) + acc.w*inv : 0.f;
    h.x = (h0 > 0.f) ? h0 : expm1f(h0);
    h.y = (h1 > 0.f) ? h1 : expm1f(h1);
    h.z = (h2 > 0.f) ? h2 : expm1f(h2);
    h.w = (h3 > 0.f) ? h3 : expm1f(h3);
  }
  if constexpr (MODE == 0){
    if (lane < 50){
      ushort4 o; o.x = f2bf(h.x); o.y = f2bf(h.y); o.z = f2bf(h.z); o.w = f2bf(h.w);
      *(ushort4*)(outb + (size_t)n*ldb + coffb + 4*lane) = o;
    }
  } else {
    float m = mask[n];
    float4 v = make_float4(0.f,0.f,0.f,0.f);
    if (lane < 50){
      ushort4 bb = *(const ushort4*)(baseb + (size_t)n*224 + 4*lane);
      v.x = bf2f(bb.x) + m*h.x;
      v.y = bf2f(bb.y) + m*h.y;
      v.z = bf2f(bb.z) + m*h.z;
      v.w = bf2f(bb.w) + m*h.w;
    }
    float ss = v.x*v.x + v.y*v.y + v.z*v.z + v.w*v.w;
    #pragma unroll
    for (int o = 32; o; o >>= 1) ss += __shfl_xor(ss, o, 64);
    float sc = 1.0f / fmaxf(sqrtf(ss), 1e-12f);
    if constexpr (MODE == 1){
      if (lane < 56){
        ushort4 o; o.x = f2bf(v.x*sc); o.y = f2bf(v.y*sc); o.z = f2bf(v.z*sc); o.w = f2bf(v.w*sc);
        *(ushort4*)(outb + (size_t)n*224 + 4*lane) = o;   // lanes 50-55 write zeros (pad cols)
      }
    } else {
      if (lane < 50)
        *(float4*)(outf + (size_t)n*200 + 4*lane) = make_float4(v.x*sc, v.y*sc, v.z*sc, v.w*sc);
    }
  }
}

template<int MODE>
__global__ __launch_bounds__(256) void k_agg5(
    const int* __restrict__ rowofs, const int4* __restrict__ erec,
    const float* __restrict__ ps, const float* __restrict__ pd, const float* __restrict__ prs,
    const __hip_bfloat16* __restrict__ XSD,
    const __hip_bfloat16* __restrict__ RRb,
    const __hip_bfloat16* __restrict__ baseb, const float* __restrict__ mask,
    __hip_bfloat16* __restrict__ outb, int ldb, int coffb, float* __restrict__ outf)
{
  __shared__ float4 redA[256];
  __shared__ float redS[4];
  int bid = blockIdx.x;
  int wave = threadIdx.x >> 6, lane = threadIdx.x & 63;

  if (bid < HOTN){
    int n = bid;
    int beg = rowofs[n], end = rowofs[n+1];
    float psn = ps[n];
    float Sl = 0.f;
    float4 acc = make_float4(0.f,0.f,0.f,0.f);
    agg5_edges(beg + wave*64, end, 256, erec, psn, pd, prs,
               XSD, 512, 256, RRb, 256, 0, lane, Sl, acc);
    float Sw = Sl;
    #pragma unroll
    for (int o = 32; o; o >>= 1) Sw += __shfl_xor(Sw, o, 64);
    redA[threadIdx.x] = acc;
    if (lane == 0) redS[wave] = Sw;
    __syncthreads();
    if (wave == 0){
      float4 q0 = redA[lane], q1 = redA[lane+64], q2 = redA[lane+128], q3 = redA[lane+192];
      float4 at = make_float4(q0.x+q1.x+q2.x+q3.x, q0.y+q1.y+q2.y+q3.y,
                              q0.z+q1.z+q2.z+q3.z, q0.w+q1.w+q2.w+q3.w);
      float St = redS[0] + redS[1] + redS[2] + redS[3];
      agg5_finalize<MODE>(n, St, at, lane, XSD, 512, 0, baseb, mask, outb, ldb, coffb, outf);
    }
  } else {
    int n = HOTN + (bid - HOTN)*4 + wave;
    int beg = rowofs[n], end = rowofs[n+1];
    float psn = ps[n];
    float Sl = 0.f;
    float4 acc = make_float4(0.f,0.f,0.f,0.f);
    agg5_edges(beg, end, 64, erec, psn, pd, prs,
               XSD, 512, 256, RRb, 256, 0, lane, Sl, acc);
    float S = Sl;
    #pragma unroll
    for (int o = 32; o; o >>= 1) S += __shfl_xor(S, o, 64);
    agg5_finalize<MODE>(n, S, acc, lane, XSD, 512, 0, baseb, mask, outb, ldb, coffb, outf);
  }
}

// ---------------------------------------------------------------- fused layer0-heads aggregation (dual-edge)
__device__ inline void aggh_edges(int bstart, int end, int bstep,
    const int4* __restrict__ erec,
    float ps0n, const float* __restrict__ pd0, const float* __restrict__ prs0,
    float ps1n, const float* __restrict__ pd1, const float* __restrict__ prs1,
    const __hip_bfloat16* __restrict__ XSD, int ldx,
    const __hip_bfloat16* __restrict__ RRb, int ldr,
    int lane, float& Sl0, float& Sl1, float4& accO)
{
  bool act = lane < 50;
  int head = (lane >= 25) ? 1 : 0;
  int li = lane - 25*head;
  const __hip_bfloat16* xb = XSD + (head ? 384 : 128) + 4*li;
  const __hip_bfloat16* rb = RRb + (head ? 128 : 0) + 4*li;
  float4 accA = make_float4(0.f,0.f,0.f,0.f);
  float4 accB = make_float4(0.f,0.f,0.f,0.f);
  for (int b = bstart; b < end; b += bstep){
    int j = b + lane;
    int4 e = make_int4(0, NRELS, NRELS, 0);
    float wv0 = 0.f, wv1 = 0.f;
    if (j < end){
      e = erec[j];
      float lg0 = ps0n + pd0[e.x] + prs0[e.y] + prs0[e.z];
      float lg1 = ps1n + pd1[e.x] + prs1[e.y] + prs1[e.z];
      wv0 = __expf(-((lg0 > 0.f) ? lg0 : 0.2f*lg0));
      wv1 = __expf(-((lg1 > 0.f) ? lg1 : 0.2f*lg1));
    }
    Sl0 += wv0; Sl1 += wv1;
    int m = end - b; if (m > 64) m = 64;
    int i = 0;
    for (; i + 1 < m; i += 2){
      float wA0 = __shfl(wv0, i),   wA1 = __shfl(wv1, i);
      float wB0 = __shfl(wv0, i+1), wB1 = __shfl(wv1, i+1);
      int dA = __shfl(e.x, i),   tA0 = __shfl(e.y, i),   tA1 = __shfl(e.z, i);
      int dB = __shfl(e.x, i+1), tB0 = __shfl(e.y, i+1), tB1 = __shfl(e.z, i+1);
      if (act){
        float wA = head ? wA1 : wA0;
        float wB = head ? wB1 : wB0;
        ushort4 xA = *(const ushort4*)(xb + (size_t)dA*ldx);
        ushort4 rA = *(const ushort4*)(rb + (size_t)tA0*ldr);
        ushort4 xB = *(const ushort4*)(xb + (size_t)dB*ldx);
        ushort4 rB = *(const ushort4*)(rb + (size_t)tB0*ldr);
        float ax = bf2f(xA.x)+bf2f(rA.x), ay = bf2f(xA.y)+bf2f(rA.y);
        float az = bf2f(xA.z)+bf2f(rA.z), aw = bf2f(xA.w)+bf2f(rA.w);
        if (tA1 != NRELS){
          ushort4 rc = *(const ushort4*)(rb + (size_t)tA1*ldr);
          ax += bf2f(rc.x); ay += bf2f(rc.y); az += bf2f(rc.z); aw += bf2f(rc.w);
        }
        float bx = bf2f(xB.x)+bf2f(rB.x), by = bf2f(xB.y)+bf2f(rB.y);
        float bz = bf2f(xB.z)+bf2f(rB.z), bw = bf2f(xB.w)+bf2f(rB.w);
        if (tB1 != NRELS){
          ushort4 rc = *(const ushort4*)(rb + (size_t)tB1*ldr);
          bx += bf2f(rc.x); by += bf2f(rc.y); bz += bf2f(rc.z); bw += bf2f(rc.w);
        }
        accA.x += wA*ax; accA.y += wA*ay; accA.z += wA*az; accA.w += wA*aw;
        accB.x += wB*bx; accB.y += wB*by; accB.z += wB*bz; accB.w += wB*bw;
      }
    }
    if (i < m){
      float wA0 = __shfl(wv0, i), wA1 = __shfl(wv1, i);
      int dA = __shfl(e.x, i), tA0 = __shfl(e.y, i), tA1 = __shfl(e.z, i);
      if (act){
        float wA = head ? wA1 : wA0;
        ushort4 xA = *(const ushort4*)(xb + (size_t)dA*ldx);
        ushort4 rA = *(const ushort4*)(rb + (size_t)tA0*ldr);
        float ax = bf2f(xA.x)+bf2f(rA.x), ay = bf2f(xA.y)+bf2f(rA.y);
        float az = bf2f(xA.z)+bf2f(rA.z), aw = bf2f(xA.w)+bf2f(rA.w);
        if (tA1 != NRELS){
          ushort4 rc = *(const ushort4*)(rb + (size_t)tA1*ldr);
          ax += bf2f(rc.x); ay += bf2f(rc.y); az += bf2f(rc.z); aw += bf2f(rc.w);
        }
        accA.x += wA*ax; accA.y += wA*ay; accA.z += wA*az; accA.w += wA*aw;
      }
    }
  }
  accO.x += accA.x + accB.x; accO.y += accA.y + accB.y;
  accO.z += accA.z + accB.z; accO.w += accA.w + accB.w;
}

__device__ inline void aggh_finalize(int n, float S0, float S1, float4 acc, int lane,
    const __hip_bfloat16* __restrict__ XSD,
    __hip_bfloat16* __restrict__ outb, int ldb)
{
  if (lane >= 50) return;
  int head = (lane >= 25) ? 1 : 0;
  int li = lane - 25*head;
  float S = head ? S1 : S0;
  float inv = (S > 0.f) ? 1.0f/S : 0.f;
  ushort4 xs4 = *(const ushort4*)(XSD + (size_t)n*512 + (head ? 256 : 0) + 4*li);
  float h0 = (S > 0.f) ? bf2f(xs4.x) + acc.x*inv : 0.f;
  float h1 = (S > 0.f) ? bf2f(xs4.y) + acc.y*inv : 0.f;
  float h2 = (S > 0.f) ? bf2f(xs4.z) + acc.z*inv : 0.f;
  float h3 = (S > 0.f) ? bf2f(xs4.w) + acc.w*inv : 0.f;
  h0 = (h0 > 0.f) ? h0 : expm1f(h0);
  h1 = (h1 > 0.f) ? h1 : expm1f(h1);
  h2 = (h2 > 0.f) ? h2 : expm1f(h2);
  h3 = (h3 > 0.f) ? h3 : expm1f(h3);
  ushort4 o; o.x = f2bf(h0); o.y = f2bf(h1); o.z = f2bf(h2); o.w = f2bf(h3);
  *(ushort4*)(outb + (size_t)n*ldb + 100*head + 4*li) = o;
}

__global__ __launch_bounds__(256) void k_aggh(
    const int* __restrict__ rowofs, const int4* __restrict__ erec,
    const float* __restrict__ ps0, const float* __restrict__ pd0, const float* __restrict__ prs0,
    const float* __restrict__ ps1, const float* __restrict__ pd1, const float* __restrict__ prs1,
    const __hip_bfloat16* __restrict__ XSD, const __hip_bfloat16* __restrict__ RRb,
    __hip_bfloat16* __restrict__ outb, int ldb)
{
  __shared__ float4 redA[256];
  __shared__ float redS0[4];
  __shared__ float redS1[4];
  int bid = blockIdx.x;
  int wave = threadIdx.x >> 6, lane = threadIdx.x & 63;

  if (bid < HOTN){
    int n = bid;
    int beg = rowofs[n], end = rowofs[n+1];
    float ps0n = ps0[n], ps1n = ps1[n];
    float Sl0 = 0.f, Sl1 = 0.f;
    float4 acc = make_float4(0.f,0.f,0.f,0.f);
    aggh_edges(beg + wave*64, end, 256, erec, ps0n, pd0, prs0, ps1n, pd1, prs1,
               XSD, 512, RRb, 256, lane, Sl0, Sl1, acc);
    float Sw0 = Sl0, Sw1 = Sl1;
    #pragma unroll
    for (int o = 32; o; o >>= 1){ Sw0 += __shfl_xor(Sw0, o, 64); Sw1 += __shfl_xor(Sw1, o, 64); }
    redA[threadIdx.x] = acc;
    if (lane == 0){ redS0[wave] = Sw0; redS1[wave] = Sw1; }
    __syncthreads();
    if (wave == 0){
      float4 q0 = redA[lane], q1 = redA[lane+64], q2 = redA[lane+128], q3 = redA[lane+192];
      float4 at = make_float4(q0.x+q1.x+q2.x+q3.x, q0.y+q1.y+q2.y+q3.y,
                              q0.z+q1.z+q2.z+q3.z, q0.w+q1.w+q2.w+q3.w);
      float St0 = redS0[0] + redS0[1] + redS0[2] + redS0[3];
      float St1 = redS1[0] + redS1[1] + redS1[2] + redS1[3];
      aggh_finalize(n, St0, St1, at, lane, XSD, outb, ldb);
    }
  } else {
    int n = HOTN + (bid - HOTN)*4 + wave;
    int beg = rowofs[n], end = rowofs[n+1];
    float ps0n = ps0[n], ps1n = ps1[n];
    float Sl0 = 0.f, Sl1 = 0.f;
    float4 acc = make_float4(0.f,0.f,0.f,0.f);
    aggh_edges(beg, end, 64, erec, ps0n, pd0, prs0, ps1n, pd1, prs1,
               XSD, 512, RRb, 256, lane, Sl0, Sl1, acc);
    float S0 = Sl0, S1 = Sl1;
    #pragma unroll
    for (int o = 32; o; o >>= 1){ S0 += __shfl_xor(S0, o, 64); S1 += __shfl_xor(S1, o, 64); }
    aggh_finalize(n, S0, S1, acc, lane, XSD, outb, ldb);
  }
}

// ---------------------------------------------------------------- driver
extern "C" void kernel_launch(void* const* d_in, const int* in_sizes, int n_in,
                              void* d_out, int out_size, void* d_ws, size_t ws_size,
                              hipStream_t stream) {
  const float* entity   = (const float*)d_in[0];
  const float* relation = (const float*)d_in[1];
  const float* W_ent    = (const float*)d_in[2];
  const float* g0_a0    = (const float*)d_in[3];
  const float* g0_s0    = (const float*)d_in[4];
  const float* g0_a1    = (const float*)d_in[5];
  const float* g0_s1    = (const float*)d_in[6];
  const float* g0_W     = (const float*)d_in[7];
  const float* g0_oa    = (const float*)d_in[8];
  const float* g0_os    = (const float*)d_in[9];
  const float* g1_a0    = (const float*)d_in[10];
  const float* g1_s0    = (const float*)d_in[11];
  const float* g1_W     = (const float*)d_in[12];
  const float* g1_oa    = (const float*)d_in[13];
  const float* g1_os    = (const float*)d_in[14];
  const int*   el       = (const int*)d_in[15];
  const int*   et       = (const int*)d_in[16];
  const int*   nh       = (const int*)d_in[17];
  const int*   batch    = (const int*)d_in[18];
  (void)in_sizes; (void)n_in; (void)out_size; (void)ws_size;

  char* w = (char*)d_ws;
  auto alloc = [&](size_t bytes)->char*{ char* p = w; w += (bytes + 255) & ~(size_t)255; return p; };
  float* PS0   = (float*)alloc((size_t)NNODES*4);
  float* PD0   = (float*)alloc((size_t)NNODES*4);
  float* PS1   = (float*)alloc((size_t)NNODES*4);
  float* PD1   = (float*)alloc((size_t)NNODES*4);
  float* PRS0  = (float*)alloc((size_t)(NRELS+4)*4);
  float* PRS1  = (float*)alloc((size_t)(NRELS+4)*4);
  float* WT    = (float*)alloc((size_t)2304*4);
  __hip_bfloat16* AENT0  = (__hip_bfloat16*)alloc((size_t)MP*128*2);
  __hip_bfloat16* AX1    = (__hip_bfloat16*)alloc((size_t)MP*224*2);
  __hip_bfloat16* AENT1  = (__hip_bfloat16*)alloc((size_t)MP*224*2);
  __hip_bfloat16* ENTUPb = (__hip_bfloat16*)alloc((size_t)MP*224*2);
  __hip_bfloat16* AREL0  = (__hip_bfloat16*)alloc((size_t)RPAD*128*2);
  __hip_bfloat16* AREL1  = (__hip_bfloat16*)alloc((size_t)RPAD*224*2);
  __hip_bfloat16* RELUPb = (__hip_bfloat16*)alloc((size_t)RPAD*224*2);
  __hip_bfloat16* ORb0   = (__hip_bfloat16*)alloc((size_t)RPAD*224*2);
  __hip_bfloat16* ORb1   = (__hip_bfloat16*)alloc((size_t)RPAD*224*2);
  __hip_bfloat16* XSD    = (__hip_bfloat16*)alloc((size_t)MP*512*2);
  __hip_bfloat16* RRb    = (__hip_bfloat16*)alloc((size_t)RPAD*256*2);
  __hip_bfloat16* WA     = (__hip_bfloat16*)alloc((size_t)737280*2);
  int* IALL = (int*)alloc((size_t)150001*4);
  int* ROWOFS = IALL;
  int* CUR    = IALL + 50001;
  float* MASK = (float*)(IALL + 100001);
  int4* EREC  = (int4*)alloc((size_t)NETOT*16);
  int* PART   = (int*)alloc((size_t)256*4);

  const __hip_bfloat16* WET   = WA;
  const __hip_bfloat16* G0WT  = WA + 32768;
  const __hip_bfloat16* BH0   = WA + 65536;
  const __hip_bfloat16* BR0   = WA + 131072;
  const __hip_bfloat16* BO0   = WA + 163840;
  const __hip_bfloat16* BO0r  = WA + 278528;
  const __hip_bfloat16* BA1   = WA + 335872;
  const __hip_bfloat16* BA1r  = WA + 450560;
  const __hip_bfloat16* G1WT  = WA + 507904;
  const __hip_bfloat16* BO1   = WA + 565248;
  const __hip_bfloat16* BO1r  = WA + 679936;

  float* outEnt = (float*)d_out;
  float* outRel = outEnt + (size_t)NNODES*200;

  const int TB = 256;
  auto gb = [&](long long n){ return (int)((n + TB - 1)/TB); };
  const int AGG_GRID = HOTN + (NNODES - HOTN)/4;
  const int RD_GRID = 12500 + 126;

  // ---- setup ----
  {
    SetupArgs a;
    a.iall = IALL; a.aent0 = AENT0; a.ax1 = AX1; a.aent1 = AENT1; a.arel0 = AREL0; a.arel1 = AREL1;
    a.wt = WT; a.s0h = g0_s0; a.s1h = g0_s1; a.os0 = g0_os; a.s1l = g1_s0; a.os1 = g1_os;
    a.wa = WA;
    a.wsrcs.p[0] = W_ent; a.wsrcs.p[1] = g0_a0; a.wsrcs.p[2] = g0_a1; a.wsrcs.p[3] = g0_W;
    a.wsrcs.p[4] = g0_oa; a.wsrcs.p[5] = g1_a0; a.wsrcs.p[6] = g1_W;  a.wsrcs.p[7] = g1_oa;
    a.entity = entity; a.relation = relation;
    k_setup<<<SB_TOT, 256, 0, stream>>>(a);
  }
  k_mask_set<<<gb(10000), TB, 0, stream>>>(batch, MASK, 10000);
  k_hist<<<gb(NETOT), TB, 0, stream>>>(el, nh, ROWOFS);
  int nsb = (NNODES + 255)/256;
  k_scan1<<<nsb, 256, 0, stream>>>(ROWOFS, NNODES, PART);
  k_scan2<<<1, 256, 0, stream>>>(PART, nsb);
  k_scan3<<<nsb, 256, 0, stream>>>(ROWOFS, NNODES, PART);
  k_scatter<<<gb(NETOT), TB, 0, stream>>>(el, et, nh, ROWOFS, CUR, EREC);

  auto mkdesc = [](const __hip_bfloat16* A, const __hip_bfloat16* B, __hip_bfloat16* C,
                   int M, int Nn, int Kp, int ldc){
    GemmDesc d; d.A = A; d.B = B; d.C = C; d.M = M; d.Nn = Nn; d.Kp = Kp; d.ldc = ldc;
    d.gx = (Nn + 63)/64; d.nblk = d.gx * ((M + 127)/128); return d;
  };
  GemmDesc dnull = {}; dnull.nblk = 0;
  auto gemm2 = [&](GemmDesc d1, GemmDesc d2){
    k_gemm2<<<d1.nblk + d2.nblk, 256, 0, stream>>>(d1, d2);
  };

  // ---- ent_up / rel_up ----
  gemm2(mkdesc(AENT0, WET, ENTUPb, MP, 200, 128, 224),
        mkdesc(AREL0, WET, RELUPb, RPAD, 200, 128, 224));

  // ---- layer0 heads ----
  gemm2(mkdesc(AENT0, BH0, XSD, MP, 512, 128, 512),
        mkdesc(AREL0, BR0, RRb, RPAD, 256, 128, 256));
  k_rowdot3<<<RD_GRID, 256, 0, stream>>>(XSD, WT + 0, 16, PS0, PD0, PS1, PD1,
                                         RRb, WT + 512, 32, PRS0, PRS1);
  k_aggh<<<AGG_GRID, 256, 0, stream>>>(ROWOFS, EREC, PS0, PD0, PRS0, PS1, PD1, PRS1,
                                       XSD, RRb, AX1, 224);

  // ---- layer0 out-attention (agg fused with combine -> AENT1) ----
  gemm2(mkdesc(AX1, BO0, XSD, MP, 512, 224, 512),
        mkdesc(AREL0, G0WT, ORb0, RPAD, 224, 128, 224));
  gemm2(mkdesc(ORb0, BO0r, RRb, RPAD, 256, 224, 256), dnull);
  k_rowdot3<<<RD_GRID, 256, 0, stream>>>(XSD, WT + 768, 32, PS0, PD0, nullptr, nullptr,
                                         RRb, WT + 768, 64, PRS0, nullptr);
  k_agg5<1><<<AGG_GRID, 256, 0, stream>>>(ROWOFS, EREC, PS0, PD0, PRS0, XSD, RRb,
                                          ENTUPb, MASK, AENT1, 224, 0, nullptr);
  k_combine_rel<false><<<NRELS, 64, 0, stream>>>(RELUPb, ORb0, nullptr, AREL1);

  // ---- layer1 head ----
  gemm2(mkdesc(AENT1, BA1, XSD, MP, 512, 224, 512),
        mkdesc(AREL1, BA1r, RRb, RPAD, 256, 224, 256));
  k_rowdot3<<<RD_GRID, 256, 0, stream>>>(XSD, WT + 1280, 32, PS0, PD0, nullptr, nullptr,
                                         RRb, WT + 1280, 64, PRS0, nullptr);
  k_agg5<0><<<AGG_GRID, 256, 0, stream>>>(ROWOFS, EREC, PS0, PD0, PRS0, XSD, RRb,
                                          nullptr, nullptr, AX1, 224, 0, nullptr);

  // ---- layer1 out-attention (agg fused with final combine -> d_out) ----
  gemm2(mkdesc(AX1, BO1, XSD, MP, 512, 224, 512),
        mkdesc(AREL1, G1WT, ORb1, RPAD, 224, 224, 224));
  gemm2(mkdesc(ORb1, BO1r, RRb, RPAD, 256, 224, 256), dnull);
  k_rowdot3<<<RD_GRID, 256, 0, stream>>>(XSD, WT + 1792, 32, PS0, PD0, nullptr, nullptr,
                                         RRb, WT + 1792, 64, PRS0, nullptr);
  k_agg5<2><<<AGG_GRID, 256, 0, stream>>>(ROWOFS, EREC, PS0, PD0, PRS0, XSD, RRb,
                                          AENT1, MASK, nullptr, 0, 0, outEnt);
  k_combine_rel<true><<<NRELS, 64, 0, stream>>>(AREL1, ORb1, outRel, nullptr);
}

// Round 14
// 549.312 us; speedup vs baseline: 1.2176x; 1.0249x over previous
//
#include <hip/hip_runtime.h>
#include <hip/hip_bf16.h>
#include <cstdint>
#include <cstddef>

#define NNODES 50000
#define NRELS  500
#define NEDGE  500000
#define NETOT  600000
#define MP     50048
#define RPAD   512
#define HOTN   512

typedef __attribute__((ext_vector_type(8))) short bf16x8;
typedef __attribute__((ext_vector_type(4))) float f32x4;

__device__ inline float bf2f(unsigned short s){
  union { unsigned u; float f; } v; v.u = ((unsigned)s) << 16; return v.f;
}
__device__ inline unsigned short f2bf(float f){
  __hip_bfloat16 h = __float2bfloat16(f);
  return __builtin_bit_cast(unsigned short, h);
}

// ---------------------------------------------------------------- weight conversion table
struct WEnt { int src, ld, boff, rows, K, tr, dstoff, Kp, rp; };
__device__ const WEnt g_went[18] = {
  {0,200,0,200,100,1,      0,128,256},
  {3,200,0,200,100,1,  32768,128,256},
  {1,300,  0,100,100,0,  65536,128,128},
  {1,300,100,100,100,0,  81920,128,128},
  {2,300,  0,100,100,0,  98304,128,128},
  {2,300,100,100,100,0, 114688,128,128},
  {1,300,200,100,100,0, 131072,128,128},
  {2,300,200,100,100,0, 147456,128,128},
  {4,600,  0,200,200,0, 163840,224,256},
  {4,600,200,200,200,0, 221184,224,256},
  {4,600,400,200,200,0, 278528,224,256},
  {5,600,  0,200,200,0, 335872,224,256},
  {5,600,200,200,200,0, 393216,224,256},
  {5,600,400,200,200,0, 450560,224,256},
  {6,200,0,200,200,1,   507904,224,256},
  {7,600,  0,200,200,0, 565248,224,256},
  {7,600,200,200,200,0, 622592,224,256},
  {7,600,400,200,200,0, 679936,224,256},
};
struct Ptr8 { const float* p[8]; };

// ---------------------------------------------------------------- mega setup kernel (segmented grid)
#define SB_O1 587
#define SB_O2 599
#define SB_O3 620
#define SB_O4 641
#define SB_O5 650
#define SB_O6 5342
#define SB_O7 5351
#define SB_O8 13415
#define SB_O9 25915
#define SB_TOT 26040

struct SetupArgs {
  int* iall;
  __hip_bfloat16 *aent0, *ax1, *aent1, *arel0, *arel1;
  float* wt;
  const float *s0h, *s1h, *os0, *s1l, *os1;
  __hip_bfloat16* wa;
  Ptr8 wsrcs;
  const float *entity, *relation;
};

__global__ __launch_bounds__(256) void k_setup(SetupArgs a){
  int bid = blockIdx.x, tid = threadIdx.x;
  if (bid < SB_O1){ int i = bid*256 + tid; if (i < 150001) a.iall[i] = 0; return; }
  if (bid < SB_O2){ int i = (bid-SB_O1)*256 + tid;
    ((int*)(a.aent0 + (size_t)NNODES*128))[i] = 0; return; }
  if (bid < SB_O3){ int i = (bid-SB_O2)*256 + tid;
    if (i < 5376) ((int*)(a.ax1 + (size_t)NNODES*224))[i] = 0; return; }
  if (bid < SB_O4){ int i = (bid-SB_O3)*256 + tid;
    if (i < 5376) ((int*)(a.aent1 + (size_t)NNODES*224))[i] = 0; return; }
  if (bid < SB_O5){ int i = (bid-SB_O4)*256 + tid;
    if (i < 768) ((int*)(a.arel0 + (size_t)NRELS*128))[i] = 0;
    else if (i < 2112) ((int*)(a.arel1 + (size_t)NRELS*224))[i - 768] = 0;
    return; }
  if (bid < SB_O6){ int i = (bid-SB_O5)*256 + tid;
    int r = i / 24, k = 200 + (i - r*24);
    a.ax1[(size_t)r*224 + k] = __float2bfloat16(0.f); return; }
  if (bid < SB_O7){
    int i = (bid-SB_O6)*256 + tid; if (i >= 2304) return;
    float v = 0.f;
    if (i < 512){ int c = i & 127; const float* s = (i < 256) ? a.s0h : a.s1h; if (c < 100) v = s[c]; }
    else if (i < 768){ int j2 = i - 512, c = j2 & 127; const float* s = (j2 < 128) ? a.s0h : a.s1h; if (c < 100) v = s[c]; }
    else { int j2 = i - 768, t = j2 >> 9, c = j2 & 255;
           const float* s = (t==0)?a.os0:(t==1)?a.s1l:a.os1; if (c < 200) v = s[c]; }
    a.wt[i] = v; return; }
  if (bid < SB_O8){
    int sb = bid - SB_O7;
    WEnt e = g_went[sb / 448];
    int i = (sb - (sb/448)*448)*256 + tid;
    if (i >= e.rp*e.Kp) return;
    int r = i / e.Kp, k = i - r*e.Kp;
    float v = 0.f;
    if (r < e.rows && k < e.K)
      v = e.tr ? a.wsrcs.p[e.src][(size_t)k*e.ld + r] : a.wsrcs.p[e.src][(size_t)r*e.ld + e.boff + k];
    a.wa[e.dstoff + i] = __float2bfloat16(v); return; }
  {
    int wave = tid >> 6, lane = tid & 63;
    const float* src; __hip_bfloat16* dst; int row;
    if (bid < SB_O9){ row = (bid - SB_O8)*4 + wave; src = a.entity; dst = a.aent0; }
    else            { row = (bid - SB_O9)*4 + wave; src = a.relation; dst = a.arel0; }
    const float* rp = src + (size_t)row*100;
    float v0 = (lane < 100) ? rp[lane] : 0.f;
    float v1 = (lane + 64 < 100) ? rp[lane + 64] : 0.f;
    float ss = v0*v0 + v1*v1;
    #pragma unroll
    for (int o = 32; o; o >>= 1) ss += __shfl_xor(ss, o, 64);
    float sc = 1.0f / fmaxf(sqrtf(ss), 1e-12f);
    __hip_bfloat16* orow = dst + (size_t)row*128;
    orow[lane] = __float2bfloat16(v0*sc);
    orow[lane + 64] = __float2bfloat16(v1*sc);
  }
}

__global__ void k_mask_set(const int* __restrict__ batch, float* __restrict__ mask, int nb){
  int i = blockIdx.x*blockDim.x + threadIdx.x;
  if (i < nb) mask[batch[3*i+2]] = 1.0f;
}

// ---------------------------------------------------------------- edge CSR
__global__ void k_hist(const int* __restrict__ el, const int* __restrict__ nh, int* __restrict__ deg){
  int e = blockIdx.x*blockDim.x + threadIdx.x;
  if (e >= NETOT) return;
  int s = (e < NEDGE) ? el[e] : nh[4*(e-NEDGE)+3];
  atomicAdd(&deg[s], 1);
}
__global__ void k_scan1(int* __restrict__ data, int n, int* __restrict__ part){
  __shared__ int sh[256];
  int t = threadIdx.x, i = blockIdx.x*256 + t;
  int v = (i < n) ? data[i] : 0;
  sh[t] = v; __syncthreads();
  for (int o = 1; o < 256; o <<= 1){
    int x = (t >= o) ? sh[t-o] : 0;
    __syncthreads(); sh[t] += x; __syncthreads();
  }
  if (i < n) data[i] = sh[t] - v;
  if (t == 255) part[blockIdx.x] = sh[255];
}
__global__ void k_scan2(int* __restrict__ part, int nb){
  __shared__ int sh[256];
  int t = threadIdx.x;
  int v = (t < nb) ? part[t] : 0;
  sh[t] = v; __syncthreads();
  for (int o = 1; o < 256; o <<= 1){
    int x = (t >= o) ? sh[t-o] : 0;
    __syncthreads(); sh[t] += x; __syncthreads();
  }
  if (t < nb) part[t] = sh[t] - v;
}
__global__ void k_scan3(int* __restrict__ data, int n, const int* __restrict__ part){
  int i = blockIdx.x*256 + threadIdx.x;
  if (i < n) data[i] += part[blockIdx.x];
  if (i == 0) data[n] = NETOT;
}
__global__ void k_scatter(const int* __restrict__ el, const int* __restrict__ et,
                          const int* __restrict__ nh, const int* __restrict__ rowofs,
                          int* __restrict__ cur, int4* __restrict__ erec){
  int e = blockIdx.x*blockDim.x + threadIdx.x;
  if (e >= NETOT) return;
  int s, d, t0, t1;
  if (e < NEDGE){ s = el[e]; d = el[NEDGE+e]; t0 = et[e]; t1 = NRELS; }
  else { int i = e - NEDGE; s = nh[4*i+3]; d = nh[4*i+0]; t0 = nh[4*i+1]; t1 = nh[4*i+2]; }
  int p = rowofs[s] + atomicAdd(&cur[s], 1);
  erec[p] = make_int4(d, t0, t1, 0);
}

// ---------------------------------------------------------------- rel-only combine: l2norm(base + h)
template<bool FINAL>
__global__ __launch_bounds__(64) void k_combine_rel(
    const __hip_bfloat16* __restrict__ base, const __hip_bfloat16* __restrict__ h,
    float* __restrict__ outf, __hip_bfloat16* __restrict__ outb)
{
  int row = blockIdx.x, lane = threadIdx.x;
  int c = lane*4;
  float4 v = make_float4(0.f,0.f,0.f,0.f);
  if (c < 200){
    ushort4 bb = *(const ushort4*)(base + (size_t)row*224 + c);
    ushort4 hh = *(const ushort4*)(h + (size_t)row*224 + c);
    v.x = bf2f(bb.x) + bf2f(hh.x);
    v.y = bf2f(bb.y) + bf2f(hh.y);
    v.z = bf2f(bb.z) + bf2f(hh.z);
    v.w = bf2f(bb.w) + bf2f(hh.w);
  }
  float ss = v.x*v.x + v.y*v.y + v.z*v.z + v.w*v.w;
  #pragma unroll
  for (int o = 32; o; o >>= 1) ss += __shfl_xor(ss, o, 64);
  float sc = 1.0f / fmaxf(sqrtf(ss), 1e-12f);
  if constexpr (FINAL){
    if (c < 200) *(float4*)(outf + (size_t)row*200 + c) = make_float4(v.x*sc, v.y*sc, v.z*sc, v.w*sc);
  } else {
    if (c < 224){
      ushort4 w4; w4.x = f2bf(v.x*sc); w4.y = f2bf(v.y*sc); w4.z = f2bf(v.z*sc); w4.w = f2bf(v.w*sc);
      *(ushort4*)(outb + (size_t)row*224 + c) = w4;
    }
  }
}

// ---------------------------------------------------------------- fused node+rel rowdot
__global__ __launch_bounds__(256) void k_rowdot3(
    const __hip_bfloat16* __restrict__ XN, const float* __restrict__ wtN, int GN,
    float* __restrict__ n0, float* __restrict__ n1, float* __restrict__ n2, float* __restrict__ n3,
    const __hip_bfloat16* __restrict__ XR, const float* __restrict__ wtR, int GR,
    float* __restrict__ r0, float* __restrict__ r1)
{
  int wave = threadIdx.x >> 6, lane = threadIdx.x & 63;
  int b = blockIdx.x;
  if (b < 12500){
    int row = b*4 + wave;
    const __hip_bfloat16* xr = XN + (size_t)row*512 + lane*8;
    const float* wr = wtN + lane*8;
    float p = 0.f;
    #pragma unroll
    for (int k = 0; k < 2; k++){
      ushort4 x = *(const ushort4*)(xr + 4*k);
      float4 a = *(const float4*)(wr + 4*k);
      p += bf2f(x.x)*a.x + bf2f(x.y)*a.y + bf2f(x.z)*a.z + bf2f(x.w)*a.w;
    }
    for (int o = GN>>1; o; o >>= 1) p += __shfl_xor(p, o, 64);
    if ((lane & (GN-1)) == 0){
      int g = lane / GN;
      float* out = (g==0)?n0:(g==1)?n1:(g==2)?n2:n3;
      out[row] = p;
    }
  } else {
    int row = (b - 12500)*4 + wave;
    if (row >= NRELS + 1) return;
    const __hip_bfloat16* xr = XR + (size_t)row*256 + lane*4;
    ushort4 x = *(const ushort4*)xr;
    float4 a = *(const float4*)(wtR + lane*4);
    float p = bf2f(x.x)*a.x + bf2f(x.y)*a.y + bf2f(x.z)*a.z + bf2f(x.w)*a.w;
    for (int o = GR>>1; o; o >>= 1) p += __shfl_xor(p, o, 64);
    if ((lane & (GR-1)) == 0){
      int g = lane / GR;
      float* out = (g==0)?r0:r1;
      out[row] = p;
    }
  }
}

// ---------------------------------------------------------------- triple bf16 MFMA GEMM (NT)
struct GemmDesc {
  const __hip_bfloat16 *A, *B; __hip_bfloat16* C;
  int M, Nn, Kp, ldc, gx, nblk;
};
__global__ __launch_bounds__(256) void k_gemm3(GemmDesc g1, GemmDesc g2, GemmDesc g3)
{
  __shared__ __hip_bfloat16 As[128*32];
  __shared__ __hip_bfloat16 Bs[64*32];
  const int tid = threadIdx.x;
  const int wave = tid >> 6, lane = tid & 63;
  const int lg = lane >> 4, li = lane & 15;
  int nwg = gridDim.x;
  int orig = blockIdx.x;
  int q = nwg >> 3, r = nwg & 7;
  int xcd = orig & 7, off = orig >> 3;
  int wg = (xcd < r ? xcd*(q+1) : r*(q+1) + (xcd - r)*q) + off;
  GemmDesc g; int local;
  if (wg < g1.nblk){ g = g1; local = wg; }
  else if (wg < g1.nblk + g2.nblk){ g = g2; local = wg - g1.nblk; }
  else { g = g3; local = wg - g1.nblk - g2.nblk; }
  const int bx = local % g.gx, by = local / g.gx;
  const int m0 = by * 128, n0 = bx * 64;
  const int Kp = g.Kp;
  const int wr = wave >> 1, wc = wave & 1;
  f32x4 acc[4][2] = {};

  const int ar0 = tid >> 2;
  const int ar1 = (tid + 256) >> 2;
  const int ap  = tid & 3;
  const char* Ab = (const char*)g.A;
  const char* Bb = (const char*)g.B;
  char* asB = (char*)As;
  char* bsB = (char*)Bs;

  for (int kk = 0; kk < Kp; kk += 32){
    {
      int p0 = ap ^ ((ar0 >> 1) & 3);
      const char* s0 = Ab + ((size_t)(m0 + ar0)*Kp + kk)*2 + p0*16;
      __builtin_amdgcn_global_load_lds((const __attribute__((address_space(1))) void*)s0,
          (__attribute__((address_space(3))) void*)(asB + wave*1024), 16, 0, 0);
      int p1 = ap ^ ((ar1 >> 1) & 3);
      const char* s1 = Ab + ((size_t)(m0 + ar1)*Kp + kk)*2 + p1*16;
      __builtin_amdgcn_global_load_lds((const __attribute__((address_space(1))) void*)s1,
          (__attribute__((address_space(3))) void*)(asB + 4096 + wave*1024), 16, 0, 0);
      int pb = ap ^ ((ar0 >> 1) & 3);
      const char* sb = Bb + ((size_t)(n0 + ar0)*Kp + kk)*2 + pb*16;
      __builtin_amdgcn_global_load_lds((const __attribute__((address_space(1))) void*)sb,
          (__attribute__((address_space(3))) void*)(bsB + wave*1024), 16, 0, 0);
    }
    __syncthreads();
    bf16x8 av[4], bv[2];
    #pragma unroll
    for (int mf = 0; mf < 4; mf++){
      int row = wr*64 + mf*16 + li;
      int p = lg ^ ((row >> 1) & 3);
      av[mf] = *(const bf16x8*)(asB + row*64 + p*16);
    }
    #pragma unroll
    for (int nf = 0; nf < 2; nf++){
      int row = wc*32 + nf*16 + li;
      int p = lg ^ ((row >> 1) & 3);
      bv[nf] = *(const bf16x8*)(bsB + row*64 + p*16);
    }
    #pragma unroll
    for (int mf = 0; mf < 4; mf++)
      #pragma unroll
      for (int nf = 0; nf < 2; nf++)
        acc[mf][nf] = __builtin_amdgcn_mfma_f32_16x16x32_bf16(av[mf], bv[nf], acc[mf][nf], 0, 0, 0);
    __syncthreads();
  }
  #pragma unroll
  for (int mf = 0; mf < 4; mf++){
    #pragma unroll
    for (int nf = 0; nf < 2; nf++){
      int gc = n0 + wc*32 + nf*16 + li;
      if (gc >= g.Nn) continue;
      int gr0 = m0 + wr*64 + mf*16 + lg*4;
      #pragma unroll
      for (int rr = 0; rr < 4; rr++){
        int gr = gr0 + rr;
        if (gr < g.M) g.C[(size_t)gr*g.ldc + gc] = __float2bfloat16(acc[mf][nf][rr]);
      }
    }
  }
}

// ---------------------------------------------------------------- aggregation (D=200), shfl dual-edge ILP
__device__ inline void agg5_edges(int bstart, int end, int bstep,
    const int4* __restrict__ erec, float psn,
    const float* __restrict__ pd, const float* __restrict__ prs,
    const __hip_bfloat16* __restrict__ XSD, int ldx, int cxd,
    const __hip_bfloat16* __restrict__ RRb, int ldr, int crr,
    int lane, float& Sl, float4& accO)
{
  bool act = lane < 50;
  const __hip_bfloat16* xb = XSD + cxd + 4*lane;
  const __hip_bfloat16* rb = RRb + crr + 4*lane;
  float4 accA = make_float4(0.f,0.f,0.f,0.f);
  float4 accB = make_float4(0.f,0.f,0.f,0.f);
  for (int b = bstart; b < end; b += bstep){
    int j = b + lane;
    int4 e = make_int4(0, NRELS, NRELS, 0);
    float wv = 0.f;
    if (j < end){
      e = erec[j];
      float lg = psn + pd[e.x] + prs[e.y] + prs[e.z];
      wv = __expf(-((lg > 0.f) ? lg : 0.2f*lg));
    }
    Sl += wv;
    int m = end - b; if (m > 64) m = 64;
    int i = 0;
    for (; i + 1 < m; i += 2){
      float wA = __shfl(wv, i),   wB = __shfl(wv, i+1);
      int dA = __shfl(e.x, i),   tA0 = __shfl(e.y, i),   tA1 = __shfl(e.z, i);
      int dB = __shfl(e.x, i+1), tB0 = __shfl(e.y, i+1), tB1 = __shfl(e.z, i+1);
      if (act){
        ushort4 xA = *(const ushort4*)(xb + (size_t)dA*ldx);
        ushort4 rA = *(const ushort4*)(rb + (size_t)tA0*ldr);
        ushort4 xB = *(const ushort4*)(xb + (size_t)dB*ldx);
        ushort4 rB = *(const ushort4*)(rb + (size_t)tB0*ldr);
        float ax = bf2f(xA.x)+bf2f(rA.x), ay = bf2f(xA.y)+bf2f(rA.y);
        float az = bf2f(xA.z)+bf2f(rA.z), aw = bf2f(xA.w)+bf2f(rA.w);
        if (tA1 != NRELS){
          ushort4 rc = *(const ushort4*)(rb + (size_t)tA1*ldr);
          ax += bf2f(rc.x); ay += bf2f(rc.y); az += bf2f(rc.z); aw += bf2f(rc.w);
        }
        float bx = bf2f(xB.x)+bf2f(rB.x), by = bf2f(xB.y)+bf2f(rB.y);
        float bz = bf2f(xB.z)+bf2f(rB.z), bw = bf2f(xB.w)+bf2f(rB.w);
        if (tB1 != NRELS){
          ushort4 rc = *(const ushort4*)(rb + (size_t)tB1*ldr);
          bx += bf2f(rc.x); by += bf2f(rc.y); bz += bf2f(rc.z); bw += bf2f(rc.w);
        }
        accA.x += wA*ax; accA.y += wA*ay; accA.z += wA*az; accA.w += wA*aw;
        accB.x += wB*bx; accB.y += wB*by; accB.z += wB*bz; accB.w += wB*bw;
      }
    }
    if (i < m){
      float wA = __shfl(wv, i);
      int dA = __shfl(e.x, i), tA0 = __shfl(e.y, i), tA1 = __shfl(e.z, i);
      if (act){
        ushort4 xA = *(const ushort4*)(xb + (size_t)dA*ldx);
        ushort4 rA = *(const ushort4*)(rb + (size_t)tA0*ldr);
        float ax = bf2f(xA.x)+bf2f(rA.x), ay = bf2f(xA.y)+bf2f(rA.y);
        float az = bf2f(xA.z)+bf2f(rA.z), aw = bf2f(xA.w)+bf2f(rA.w);
        if (tA1 != NRELS){
          ushort4 rc = *(const ushort4*)(rb + (size_t)tA1*ldr);
          ax += bf2f(rc.x); ay += bf2f(rc.y); az += bf2f(rc.z); aw += bf2f(rc.w);
        }
        accA.x += wA*ax; accA.y += wA*ay; accA.z += wA*az; accA.w += wA*aw;
      }
    }
  }
  accO.x += accA.x + accB.x; accO.y += accA.y + accB.y;
  accO.z += accA.z + accB.z; accO.w += accA.w + accB.w;
}

// MODE 0: bf16 out (plain). MODE 1: l2norm(base + mask*h) -> bf16 (ld224, pad cols zeroed).
// MODE 2: l2norm(base + mask*h) -> fp32 (ld200).
template<int MODE>
__device__ inline void agg5_finalize(int n, float S, float4 acc, int lane,
    const __hip_bfloat16* __restrict__ XSD, int ldx, int cxs,
    const __hip_bfloat16* __restrict__ baseb, const float* __restrict__ mask,
    __hip_bfloat16* __restrict__ outb, int ldb, int coffb, float* __restrict__ outf)
{
  float4 h = make_float4(0.f,0.f,0.f,0.f);
  if (lane < 50){
    float inv = (S > 0.f) ? 1.0f/S : 0.f;
    ushort4 xs4 = *(const ushort4*)(XSD + (size_t)n*ldx + cxs + 4*lane);
    float h0 = (S > 0.f) ? bf2f(xs4.x) + acc.x*inv : 0.f;
    float h1 = (S > 0.f) ? bf2f(xs4.y) + acc.y*inv : 0.f;
    float h2 = (S > 0.f) ? bf2f(xs4.z) + acc.z*inv : 0.f;
    float h3 = (S > 0.f) ? bf2f(xs4.w) + acc.w*inv : 0.f;
    h.x = (h0 > 0.f) ? h0 : expm1f(h0);
    h.y = (h1 > 0.f) ? h1 : expm1f(h1);
    h.z = (h2 > 0.f) ? h2 : expm1f(h2);
    h.w = (h3 > 0.f) ? h3 : expm1f(h3);
  }
  if constexpr (MODE == 0){
    if (lane < 50){
      ushort4 o; o.x = f2bf(h.x); o.y = f2bf(h.y); o.z = f2bf(h.z); o.w = f2bf(h.w);
      *(ushort4*)(outb + (size_t)n*ldb + coffb + 4*lane) = o;
    }
  } else {
    float m = mask[n];
    float4 v = make_float4(0.f,0.f,0.f,0.f);
    if (lane < 50){
      ushort4 bb = *(const ushort4*)(baseb + (size_t)n*224 + 4*lane);
      v.x = bf2f(bb.x) + m*h.x;
      v.y = bf2f(bb.y) + m*h.y;
      v.z = bf2f(bb.z) + m*h.z;
      v.w = bf2f(bb.w) + m*h.w;
    }
    float ss = v.x*v.x + v.y*v.y + v.z*v.z + v.w*v.w;
    #pragma unroll
    for (int o = 32; o; o >>= 1) ss += __shfl_xor(ss, o, 64);
    float sc = 1.0f / fmaxf(sqrtf(ss), 1e-12f);
    if constexpr (MODE == 1){
      if (lane < 56){
        ushort4 o; o.x = f2bf(v.x*sc); o.y = f2bf(v.y*sc); o.z = f2bf(v.z*sc); o.w = f2bf(v.w*sc);
        *(ushort4*)(outb + (size_t)n*224 + 4*lane) = o;   // lanes 50-55 write zeros (pad cols)
      }
    } else {
      if (lane < 50)
        *(float4*)(outf + (size_t)n*200 + 4*lane) = make_float4(v.x*sc, v.y*sc, v.z*sc, v.w*sc);
    }
  }
}

template<int MODE>
__global__ __launch_bounds__(256) void k_agg5(
    const int* __restrict__ rowofs, const int4* __restrict__ erec,
    const float* __restrict__ ps, const float* __restrict__ pd, const float* __restrict__ prs,
    const __hip_bfloat16* __restrict__ XSD,
    const __hip_bfloat16* __restrict__ RRb,
    const __hip_bfloat16* __restrict__ baseb, const float* __restrict__ mask,
    __hip_bfloat16* __restrict__ outb, int ldb, int coffb, float* __restrict__ outf)
{
  __shared__ float4 redA[256];
  __shared__ float redS[4];
  int bid = blockIdx.x;
  int wave = threadIdx.x >> 6, lane = threadIdx.x & 63;

  if (bid < HOTN){
    int n = bid;
    int beg = rowofs[n], end = rowofs[n+1];
    float psn = ps[n];
    float Sl = 0.f;
    float4 acc = make_float4(0.f,0.f,0.f,0.f);
    agg5_edges(beg + wave*64, end, 256, erec, psn, pd, prs,
               XSD, 512, 256, RRb, 256, 0, lane, Sl, acc);
    float Sw = Sl;
    #pragma unroll
    for (int o = 32; o; o >>= 1) Sw += __shfl_xor(Sw, o, 64);
    redA[threadIdx.x] = acc;
    if (lane == 0) redS[wave] = Sw;
    __syncthreads();
    if (wave == 0){
      float4 q0 = redA[lane], q1 = redA[lane+64], q2 = redA[lane+128], q3 = redA[lane+192];
      float4 at = make_float4(q0.x+q1.x+q2.x+q3.x, q0.y+q1.y+q2.y+q3.y,
                              q0.z+q1.z+q2.z+q3.z, q0.w+q1.w+q2.w+q3.w);
      float St = redS[0] + redS[1] + redS[2] + redS[3];
      agg5_finalize<MODE>(n, St, at, lane, XSD, 512, 0, baseb, mask, outb, ldb, coffb, outf);
    }
  } else {
    int n = HOTN + (bid - HOTN)*4 + wave;
    int beg = rowofs[n], end = rowofs[n+1];
    float psn = ps[n];
    float Sl = 0.f;
    float4 acc = make_float4(0.f,0.f,0.f,0.f);
    agg5_edges(beg, end, 64, erec, psn, pd, prs,
               XSD, 512, 256, RRb, 256, 0, lane, Sl, acc);
    float S = Sl;
    #pragma unroll
    for (int o = 32; o; o >>= 1) S += __shfl_xor(S, o, 64);
    agg5_finalize<MODE>(n, S, acc, lane, XSD, 512, 0, baseb, mask, outb, ldb, coffb, outf);
  }
}

// ---------------------------------------------------------------- fused layer0-heads aggregation (dual-edge)
__device__ inline void aggh_edges(int bstart, int end, int bstep,
    const int4* __restrict__ erec,
    float ps0n, const float* __restrict__ pd0, const float* __restrict__ prs0,
    float ps1n, const float* __restrict__ pd1, const float* __restrict__ prs1,
    const __hip_bfloat16* __restrict__ XSD, int ldx,
    const __hip_bfloat16* __restrict__ RRb, int ldr,
    int lane, float& Sl0, float& Sl1, float4& accO)
{
  bool act = lane < 50;
  int head = (lane >= 25) ? 1 : 0;
  int li = lane - 25*head;
  const __hip_bfloat16* xb = XSD + (head ? 384 : 128) + 4*li;
  const __hip_bfloat16* rb = RRb + (head ? 128 : 0) + 4*li;
  float4 accA = make_float4(0.f,0.f,0.f,0.f);
  float4 accB = make_float4(0.f,0.f,0.f,0.f);
  for (int b = bstart; b < end; b += bstep){
    int j = b + lane;
    int4 e = make_int4(0, NRELS, NRELS, 0);
    float wv0 = 0.f, wv1 = 0.f;
    if (j < end){
      e = erec[j];
      float lg0 = ps0n + pd0[e.x] + prs0[e.y] + prs0[e.z];
      float lg1 = ps1n + pd1[e.x] + prs1[e.y] + prs1[e.z];
      wv0 = __expf(-((lg0 > 0.f) ? lg0 : 0.2f*lg0));
      wv1 = __expf(-((lg1 > 0.f) ? lg1 : 0.2f*lg1));
    }
    Sl0 += wv0; Sl1 += wv1;
    int m = end - b; if (m > 64) m = 64;
    int i = 0;
    for (; i + 1 < m; i += 2){
      float wA0 = __shfl(wv0, i),   wA1 = __shfl(wv1, i);
      float wB0 = __shfl(wv0, i+1), wB1 = __shfl(wv1, i+1);
      int dA = __shfl(e.x, i),   tA0 = __shfl(e.y, i),   tA1 = __shfl(e.z, i);
      int dB = __shfl(e.x, i+1), tB0 = __shfl(e.y, i+1), tB1 = __shfl(e.z, i+1);
      if (act){
        float wA = head ? wA1 : wA0;
        float wB = head ? wB1 : wB0;
        ushort4 xA = *(const ushort4*)(xb + (size_t)dA*ldx);
        ushort4 rA = *(const ushort4*)(rb + (size_t)tA0*ldr);
        ushort4 xB = *(const ushort4*)(xb + (size_t)dB*ldx);
        ushort4 rB = *(const ushort4*)(rb + (size_t)tB0*ldr);
        float ax = bf2f(xA.x)+bf2f(rA.x), ay = bf2f(xA.y)+bf2f(rA.y);
        float az = bf2f(xA.z)+bf2f(rA.z), aw = bf2f(xA.w)+bf2f(rA.w);
        if (tA1 != NRELS){
          ushort4 rc = *(const ushort4*)(rb + (size_t)tA1*ldr);
          ax += bf2f(rc.x); ay += bf2f(rc.y); az += bf2f(rc.z); aw += bf2f(rc.w);
        }
        float bx = bf2f(xB.x)+bf2f(rB.x), by = bf2f(xB.y)+bf2f(rB.y);
        float bz = bf2f(xB.z)+bf2f(rB.z), bw = bf2f(xB.w)+bf2f(rB.w);
        if (tB1 != NRELS){
          ushort4 rc = *(const ushort4*)(rb + (size_t)tB1*ldr);
          bx += bf2f(rc.x); by += bf2f(rc.y); bz += bf2f(rc.z); bw += bf2f(rc.w);
        }
        accA.x += wA*ax; accA.y += wA*ay; accA.z += wA*az; accA.w += wA*aw;
        accB.x += wB*bx; accB.y += wB*by; accB.z += wB*bz; accB.w += wB*bw;
      }
    }
    if (i < m){
      float wA0 = __shfl(wv0, i), wA1 = __shfl(wv1, i);
      int dA = __shfl(e.x, i), tA0 = __shfl(e.y, i), tA1 = __shfl(e.z, i);
      if (act){
        float wA = head ? wA1 : wA0;
        ushort4 xA = *(const ushort4*)(xb + (size_t)dA*ldx);
        ushort4 rA = *(const ushort4*)(rb + (size_t)tA0*ldr);
        float ax = bf2f(xA.x)+bf2f(rA.x), ay = bf2f(xA.y)+bf2f(rA.y);
        float az = bf2f(xA.z)+bf2f(rA.z), aw = bf2f(xA.w)+bf2f(rA.w);
        if (tA1 != NRELS){
          ushort4 rc = *(const ushort4*)(rb + (size_t)tA1*ldr);
          ax += bf2f(rc.x); ay += bf2f(rc.y); az += bf2f(rc.z); aw += bf2f(rc.w);
        }
        accA.x += wA*ax; accA.y += wA*ay; accA.z += wA*az; accA.w += wA*aw;
      }
    }
  }
  accO.x += accA.x + accB.x; accO.y += accA.y + accB.y;
  accO.z += accA.z + accB.z; accO.w += accA.w + accB.w;
}

__device__ inline void aggh_finalize(int n, float S0, float S1, float4 acc, int lane,
    const __hip_bfloat16* __restrict__ XSD,
    __hip_bfloat16* __restrict__ outb, int ldb)
{
  if (lane >= 50) return;
  int head = (lane >= 25) ? 1 : 0;
  int li = lane - 25*head;
  float S = head ? S1 : S0;
  float inv = (S > 0.f) ? 1.0f/S : 0.f;
  ushort4 xs4 = *(const ushort4*)(XSD + (size_t)n*512 + (head ? 256 : 0) + 4*li);
  float h0 = (S > 0.f) ? bf2f(xs4.x) + acc.x*inv : 0.f;
  float h1 = (S > 0.f) ? bf2f(xs4.y) + acc.y*inv : 0.f;
  float h2 = (S > 0.f) ? bf2f(xs4.z) + acc.z*inv : 0.f;
  float h3 = (S > 0.f) ? bf2f(xs4.w) + acc.w*inv : 0.f;
  h0 = (h0 > 0.f) ? h0 : expm1f(h0);
  h1 = (h1 > 0.f) ? h1 : expm1f(h1);
  h2 = (h2 > 0.f) ? h2 : expm1f(h2);
  h3 = (h3 > 0.f) ? h3 : expm1f(h3);
  ushort4 o; o.x = f2bf(h0); o.y = f2bf(h1); o.z = f2bf(h2); o.w = f2bf(h3);
  *(ushort4*)(outb + (size_t)n*ldb + 100*head + 4*li) = o;
}

__global__ __launch_bounds__(256) void k_aggh(
    const int* __restrict__ rowofs, const int4* __restrict__ erec,
    const float* __restrict__ ps0, const float* __restrict__ pd0, const float* __restrict__ prs0,
    const float* __restrict__ ps1, const float* __restrict__ pd1, const float* __restrict__ prs1,
    const __hip_bfloat16* __restrict__ XSD, const __hip_bfloat16* __restrict__ RRb,
    __hip_bfloat16* __restrict__ outb, int ldb)
{
  __shared__ float4 redA[256];
  __shared__ float redS0[4];
  __shared__ float redS1[4];
  int bid = blockIdx.x;
  int wave = threadIdx.x >> 6, lane = threadIdx.x & 63;

  if (bid < HOTN){
    int n = bid;
    int beg = rowofs[n], end = rowofs[n+1];
    float ps0n = ps0[n], ps1n = ps1[n];
    float Sl0 = 0.f, Sl1 = 0.f;
    float4 acc = make_float4(0.f,0.f,0.f,0.f);
    aggh_edges(beg + wave*64, end, 256, erec, ps0n, pd0, prs0, ps1n, pd1, prs1,
               XSD, 512, RRb, 256, lane, Sl0, Sl1, acc);
    float Sw0 = Sl0, Sw1 = Sl1;
    #pragma unroll
    for (int o = 32; o; o >>= 1){ Sw0 += __shfl_xor(Sw0, o, 64); Sw1 += __shfl_xor(Sw1, o, 64); }
    redA[threadIdx.x] = acc;
    if (lane == 0){ redS0[wave] = Sw0; redS1[wave] = Sw1; }
    __syncthreads();
    if (wave == 0){
      float4 q0 = redA[lane], q1 = redA[lane+64], q2 = redA[lane+128], q3 = redA[lane+192];
      float4 at = make_float4(q0.x+q1.x+q2.x+q3.x, q0.y+q1.y+q2.y+q3.y,
                              q0.z+q1.z+q2.z+q3.z, q0.w+q1.w+q2.w+q3.w);
      float St0 = redS0[0] + redS0[1] + redS0[2] + redS0[3];
      float St1 = redS1[0] + redS1[1] + redS1[2] + redS1[3];
      aggh_finalize(n, St0, St1, at, lane, XSD, outb, ldb);
    }
  } else {
    int n = HOTN + (bid - HOTN)*4 + wave;
    int beg = rowofs[n], end = rowofs[n+1];
    float ps0n = ps0[n], ps1n = ps1[n];
    float Sl0 = 0.f, Sl1 = 0.f;
    float4 acc = make_float4(0.f,0.f,0.f,0.f);
    aggh_edges(beg, end, 64, erec, ps0n, pd0, prs0, ps1n, pd1, prs1,
               XSD, 512, RRb, 256, lane, Sl0, Sl1, acc);
    float S0 = Sl0, S1 = Sl1;
    #pragma unroll
    for (int o = 32; o; o >>= 1){ S0 += __shfl_xor(S0, o, 64); S1 += __shfl_xor(S1, o, 64); }
    aggh_finalize(n, S0, S1, acc, lane, XSD, outb, ldb);
  }
}

// ---------------------------------------------------------------- driver
extern "C" void kernel_launch(void* const* d_in, const int* in_sizes, int n_in,
                              void* d_out, int out_size, void* d_ws, size_t ws_size,
                              hipStream_t stream) {
  const float* entity   = (const float*)d_in[0];
  const float* relation = (const float*)d_in[1];
  const float* W_ent    = (const float*)d_in[2];
  const float* g0_a0    = (const float*)d_in[3];
  const float* g0_s0    = (const float*)d_in[4];
  const float* g0_a1    = (const float*)d_in[5];
  const float* g0_s1    = (const float*)d_in[6];
  const float* g0_W     = (const float*)d_in[7];
  const float* g0_oa    = (const float*)d_in[8];
  const float* g0_os    = (const float*)d_in[9];
  const float* g1_a0    = (const float*)d_in[10];
  const float* g1_s0    = (const float*)d_in[11];
  const float* g1_W     = (const float*)d_in[12];
  const float* g1_oa    = (const float*)d_in[13];
  const float* g1_os    = (const float*)d_in[14];
  const int*   el       = (const int*)d_in[15];
  const int*   et       = (const int*)d_in[16];
  const int*   nh       = (const int*)d_in[17];
  const int*   batch    = (const int*)d_in[18];
  (void)in_sizes; (void)n_in; (void)out_size; (void)ws_size;

  char* w = (char*)d_ws;
  auto alloc = [&](size_t bytes)->char*{ char* p = w; w += (bytes + 255) & ~(size_t)255; return p; };
  float* PS0   = (float*)alloc((size_t)NNODES*4);
  float* PD0   = (float*)alloc((size_t)NNODES*4);
  float* PS1   = (float*)alloc((size_t)NNODES*4);
  float* PD1   = (float*)alloc((size_t)NNODES*4);
  float* PRS0  = (float*)alloc((size_t)(NRELS+4)*4);
  float* PRS1  = (float*)alloc((size_t)(NRELS+4)*4);
  float* WT    = (float*)alloc((size_t)2304*4);
  __hip_bfloat16* AENT0  = (__hip_bfloat16*)alloc((size_t)MP*128*2);
  __hip_bfloat16* AX1    = (__hip_bfloat16*)alloc((size_t)MP*224*2);
  __hip_bfloat16* AENT1  = (__hip_bfloat16*)alloc((size_t)MP*224*2);
  __hip_bfloat16* ENTUPb = (__hip_bfloat16*)alloc((size_t)MP*224*2);
  __hip_bfloat16* AREL0  = (__hip_bfloat16*)alloc((size_t)RPAD*128*2);
  __hip_bfloat16* AREL1  = (__hip_bfloat16*)alloc((size_t)RPAD*224*2);
  __hip_bfloat16* RELUPb = (__hip_bfloat16*)alloc((size_t)RPAD*224*2);
  __hip_bfloat16* ORb0   = (__hip_bfloat16*)alloc((size_t)RPAD*224*2);
  __hip_bfloat16* ORb1   = (__hip_bfloat16*)alloc((size_t)RPAD*224*2);
  __hip_bfloat16* XSD    = (__hip_bfloat16*)alloc((size_t)MP*512*2);
  __hip_bfloat16* RRb    = (__hip_bfloat16*)alloc((size_t)RPAD*256*2);
  __hip_bfloat16* WA     = (__hip_bfloat16*)alloc((size_t)737280*2);
  int* IALL = (int*)alloc((size_t)150001*4);
  int* ROWOFS = IALL;
  int* CUR    = IALL + 50001;
  float* MASK = (float*)(IALL + 100001);
  int4* EREC  = (int4*)alloc((size_t)NETOT*16);
  int* PART   = (int*)alloc((size_t)256*4);

  const __hip_bfloat16* WET   = WA;
  const __hip_bfloat16* G0WT  = WA + 32768;
  const __hip_bfloat16* BH0   = WA + 65536;
  const __hip_bfloat16* BR0   = WA + 131072;
  const __hip_bfloat16* BO0   = WA + 163840;
  const __hip_bfloat16* BO0r  = WA + 278528;
  const __hip_bfloat16* BA1   = WA + 335872;
  const __hip_bfloat16* BA1r  = WA + 450560;
  const __hip_bfloat16* G1WT  = WA + 507904;
  const __hip_bfloat16* BO1   = WA + 565248;
  const __hip_bfloat16* BO1r  = WA + 679936;

  float* outEnt = (float*)d_out;
  float* outRel = outEnt + (size_t)NNODES*200;

  const int TB = 256;
  auto gb = [&](long long n){ return (int)((n + TB - 1)/TB); };
  const int AGG_GRID = HOTN + (NNODES - HOTN)/4;
  const int RD_GRID = 12500 + 126;

  // ---- setup ----
  {
    SetupArgs a;
    a.iall = IALL; a.aent0 = AENT0; a.ax1 = AX1; a.aent1 = AENT1; a.arel0 = AREL0; a.arel1 = AREL1;
    a.wt = WT; a.s0h = g0_s0; a.s1h = g0_s1; a.os0 = g0_os; a.s1l = g1_s0; a.os1 = g1_os;
    a.wa = WA;
    a.wsrcs.p[0] = W_ent; a.wsrcs.p[1] = g0_a0; a.wsrcs.p[2] = g0_a1; a.wsrcs.p[3] = g0_W;
    a.wsrcs.p[4] = g0_oa; a.wsrcs.p[5] = g1_a0; a.wsrcs.p[6] = g1_W;  a.wsrcs.p[7] = g1_oa;
    a.entity = entity; a.relation = relation;
    k_setup<<<SB_TOT, 256, 0, stream>>>(a);
  }
  k_mask_set<<<gb(10000), TB, 0, stream>>>(batch, MASK, 10000);
  k_hist<<<gb(NETOT), TB, 0, stream>>>(el, nh, ROWOFS);
  int nsb = (NNODES + 255)/256;
  k_scan1<<<nsb, 256, 0, stream>>>(ROWOFS, NNODES, PART);
  k_scan2<<<1, 256, 0, stream>>>(PART, nsb);
  k_scan3<<<nsb, 256, 0, stream>>>(ROWOFS, NNODES, PART);
  k_scatter<<<gb(NETOT), TB, 0, stream>>>(el, et, nh, ROWOFS, CUR, EREC);

  auto mkdesc = [](const __hip_bfloat16* A, const __hip_bfloat16* B, __hip_bfloat16* C,
                   int M, int Nn, int Kp, int ldc){
    GemmDesc d; d.A = A; d.B = B; d.C = C; d.M = M; d.Nn = Nn; d.Kp = Kp; d.ldc = ldc;
    d.gx = (Nn + 63)/64; d.nblk = d.gx * ((M + 127)/128); return d;
  };
  GemmDesc dnull = {}; dnull.nblk = 0;
  auto gemm3 = [&](GemmDesc d1, GemmDesc d2, GemmDesc d3){
    k_gemm3<<<d1.nblk + d2.nblk + d3.nblk, 256, 0, stream>>>(d1, d2, d3);
  };

  // ---- ent_up / rel_up / out_rel0 (ORb0 depends only on setup -> hoisted) ----
  gemm3(mkdesc(AENT0, WET, ENTUPb, MP, 200, 128, 224),
        mkdesc(AREL0, WET, RELUPb, RPAD, 200, 128, 224),
        mkdesc(AREL0, G0WT, ORb0, RPAD, 224, 128, 224));

  // ---- layer0 heads ----
  gemm3(mkdesc(AENT0, BH0, XSD, MP, 512, 128, 512),
        mkdesc(AREL0, BR0, RRb, RPAD, 256, 128, 256), dnull);
  k_rowdot3<<<RD_GRID, 256, 0, stream>>>(XSD, WT + 0, 16, PS0, PD0, PS1, PD1,
                                         RRb, WT + 512, 32, PRS0, PRS1);
  k_aggh<<<AGG_GRID, 256, 0, stream>>>(ROWOFS, EREC, PS0, PD0, PRS0, PS1, PD1, PRS1,
                                       XSD, RRb, AX1, 224);

  // ---- layer0 out-attention (agg fused with combine -> AENT1) ----
  gemm3(mkdesc(AX1, BO0, XSD, MP, 512, 224, 512),
        mkdesc(ORb0, BO0r, RRb, RPAD, 256, 224, 256), dnull);
  k_rowdot3<<<RD_GRID, 256, 0, stream>>>(XSD, WT + 768, 32, PS0, PD0, nullptr, nullptr,
                                         RRb, WT + 768, 64, PRS0, nullptr);
  k_agg5<1><<<AGG_GRID, 256, 0, stream>>>(ROWOFS, EREC, PS0, PD0, PRS0, XSD, RRb,
                                          ENTUPb, MASK, AENT1, 224, 0, nullptr);
  k_combine_rel<false><<<NRELS, 64, 0, stream>>>(RELUPb, ORb0, nullptr, AREL1);

  // ---- layer1 head (+ ORb1 bundled: depends only on AREL1) ----
  gemm3(mkdesc(AENT1, BA1, XSD, MP, 512, 224, 512),
        mkdesc(AREL1, BA1r, RRb, RPAD, 256, 224, 256),
        mkdesc(AREL1, G1WT, ORb1, RPAD, 224, 224, 224));
  k_rowdot3<<<RD_GRID, 256, 0, stream>>>(XSD, WT + 1280, 32, PS0, PD0, nullptr, nullptr,
                                         RRb, WT + 1280, 64, PRS0, nullptr);
  k_agg5<0><<<AGG_GRID, 256, 0, stream>>>(ROWOFS, EREC, PS0, PD0, PRS0, XSD, RRb,
                                          nullptr, nullptr, AX1, 224, 0, nullptr);

  // ---- layer1 out-attention (agg fused with final combine -> d_out) ----
  gemm3(mkdesc(AX1, BO1, XSD, MP, 512, 224, 512),
        mkdesc(ORb1, BO1r, RRb, RPAD, 256, 224, 256), dnull);
  k_rowdot3<<<RD_GRID, 256, 0, stream>>>(XSD, WT + 1792, 32, PS0, PD0, nullptr, nullptr,
                                         RRb, WT + 1792, 64, PRS0, nullptr);
  k_agg5<2><<<AGG_GRID, 256, 0, stream>>>(ROWOFS, EREC, PS0, PD0, PRS0, XSD, RRb,
                                          AENT1, MASK, nullptr, 0, 0, outEnt);
  k_combine_rel<true><<<NRELS, 64, 0, stream>>>(AREL1, ORb1, outRel, nullptr);
}